// Round 9
// baseline (106.924 us; speedup 1.0000x reference)
//
#include <hip/hip_runtime.h>
#include <stdint.h>

#define S_LEN 2048
#define DMODEL 1024
#define NHEAD 16
#define HDIM 64
#define NE 3072
#define C2 0.18033688011112042f  // 0.125 * log2(e)

typedef __attribute__((ext_vector_type(8))) short short8_t;
typedef __attribute__((ext_vector_type(4))) float f32x4;
typedef __attribute__((ext_vector_type(16))) float f32x16;

__device__ __forceinline__ float bf2f(ushort u) {
  union { float f; uint32_t i; } c; c.i = ((uint32_t)u) << 16; return c.f;
}
__device__ __forceinline__ ushort f2bf(float f) {
  union { float f; uint32_t i; } c; c.f = f;
  uint32_t x = c.i;
  return (ushort)((x + 0x7fffu + ((x >> 16) & 1u)) >> 16);
}

__device__ __forceinline__ void gload_lds16(const ushort* g, ushort* l) {
  __builtin_amdgcn_global_load_lds(
      (const __attribute__((address_space(1))) void*)g,
      (__attribute__((address_space(3))) void*)l, 16, 0, 0);
}

// ---------------- fused fp32 -> bf16 convert (x, w_in, w_out) ----------------
__global__ void cvt_all(const float* __restrict__ x, const float* __restrict__ w_in,
                        const float* __restrict__ w_out,
                        ushort* __restrict__ xbf, ushort* __restrict__ winbf,
                        ushort* __restrict__ woutbf) {
  int i = blockIdx.x * blockDim.x + threadIdx.x;
  const float* src; ushort* dst; int off;
  if (i < 524288)       { src = x;     dst = xbf;    off = i; }
  else if (i < 1310720) { src = w_in;  dst = winbf;  off = i - 524288; }
  else                  { src = w_out; dst = woutbf; off = i - 1310720; }
  float4 v = ((const float4*)src)[off];
  ushort4 o;
  o.x = f2bf(v.x); o.y = f2bf(v.y); o.z = f2bf(v.z); o.w = f2bf(v.w);
  ((ushort4*)dst)[off] = o;
}

// ---------------- bf16 GEMM: C[M][N] = A[M][K] * B[N][K]^T ----------------
template<int BM, int BN, int OUT_BF16>
__global__ __launch_bounds__(256) void gemm_abt(
    const ushort* __restrict__ A, const ushort* __restrict__ B,
    void* __restrict__ Cv, int M, int N, int K)
{
  constexpr int AR = BM / 32;
  constexpr int AC = BN / 32;
  constexpr int NG = (BM + BN) / 16;
  constexpr int PG = NG / 4;
  __shared__ ushort lds[(BM + BN) * 32];

  const int nbn = N / BN;
  const int cpx = gridDim.x >> 3;
  const int bid = blockIdx.x;
  const int swz = (bid & 7) * cpx + (bid >> 3);
  const int bm = swz / nbn;
  const int bn = swz - bm * nbn;
  const int tid = threadIdx.x;
  const int w = tid >> 6, l = tid & 63;
  const int wm = w >> 1, wn = w & 1;
  const int fr = l & 15, fg = l >> 4;

  f32x4 acc[AR][AC];
#pragma unroll
  for (int r = 0; r < AR; ++r)
#pragma unroll
    for (int c = 0; c < AC; ++c) acc[r][c] = (f32x4){0.f, 0.f, 0.f, 0.f};

  const ushort* gsrc[PG];
  ushort* ldst[PG];
#pragma unroll
  for (int i = 0; i < PG; ++i) {
    int c = w + 4 * i;
    if (c < BM / 16) {
      gsrc[i] = A + (size_t)(bm * BM + c * 16 + (l >> 2)) * K + (l & 3) * 8;
      ldst[i] = &lds[c * 512];
    } else {
      int c2 = c - BM / 16;
      gsrc[i] = B + (size_t)(bn * BN + c2 * 16 + (l >> 2)) * K + (l & 3) * 8;
      ldst[i] = &lds[BM * 32 + c2 * 512];
    }
  }

  const ushort* fa = &lds[(wm * (BM / 2) + fr) * 32 + fg * 8];
  const ushort* fb = &lds[BM * 32 + (wn * (BN / 2) + fr) * 32 + fg * 8];

  for (int k0 = 0; k0 < K; k0 += 32) {
    __syncthreads();
#pragma unroll
    for (int i = 0; i < PG; ++i) gload_lds16(gsrc[i] + k0, ldst[i]);
    __syncthreads();

    short8_t af[AR], bfr[AC];
#pragma unroll
    for (int r = 0; r < AR; ++r) {
      union { short8_t v; uint4 q; } u;
      u.q = *(const uint4*)(fa + r * 512);
      af[r] = u.v;
    }
#pragma unroll
    for (int c = 0; c < AC; ++c) {
      union { short8_t v; uint4 q; } u;
      u.q = *(const uint4*)(fb + c * 512);
      bfr[c] = u.v;
    }
    __builtin_amdgcn_s_setprio(1);
#pragma unroll
    for (int r = 0; r < AR; ++r)
#pragma unroll
      for (int c = 0; c < AC; ++c)
        acc[r][c] = __builtin_amdgcn_mfma_f32_16x16x32_bf16(af[r], bfr[c], acc[r][c], 0, 0, 0);
    __builtin_amdgcn_s_setprio(0);
  }

  const int row0 = bm * BM + wm * (BM / 2) + fg * 4;
  const int col0 = bn * BN + wn * (BN / 2) + fr;
#pragma unroll
  for (int r = 0; r < AR; ++r)
#pragma unroll
    for (int c = 0; c < AC; ++c)
#pragma unroll
      for (int j = 0; j < 4; ++j) {
        int row = row0 + r * 16 + j;
        int col = col0 + c * 16;
        if (OUT_BF16)
          ((ushort*)Cv)[(size_t)row * N + col] = f2bf(acc[r][c][j]);
        else
          ((float*)Cv)[(size_t)row * N + col] = acc[r][c][j];
      }
}

// ---------------- RoPE in-place on Q and K sections of qkv ----------------
__global__ void rope_kernel(ushort* __restrict__ qkv) {
  int idx = blockIdx.x * blockDim.x + threadIdx.x;
  int i = idx & 31;
  int hh = (idx >> 5) & (NHEAD - 1);
  int sec = (idx >> 9) & 1;
  int srow = idx >> 10;
  float invf = exp2f((float)i * (-13.287712379549449f / 32.f));
  float ang = (float)srow * invf;
  float sn, c;
  sincosf(ang, &sn, &c);
  size_t base = (size_t)srow * NE + (size_t)sec * DMODEL + hh * HDIM;
  float x1 = bf2f(qkv[base + i]);
  float x2 = bf2f(qkv[base + i + 32]);
  qkv[base + i]      = f2bf(x1 * c - x2 * sn);
  qkv[base + i + 32] = f2bf(x2 * c + x1 * sn);
}

// ---------------- V transpose: qkv V-section -> vt[h][d][key] ----------------
__global__ __launch_bounds__(256) void transpose_v(
    const ushort* __restrict__ qkv, ushort* __restrict__ vt)
{
  __shared__ ushort t[64][72];
  const int h = blockIdx.x & 15, c = blockIdx.x >> 4;
  const int tid = threadIdx.x;
#pragma unroll
  for (int j = 0; j < 2; ++j) {
    int idx = tid + 256 * j;
    int key = idx >> 3, d8 = (idx & 7) << 3;
    uint4 v = *(const uint4*)(qkv + (size_t)(c * 64 + key) * NE + 2 * DMODEL + h * HDIM + d8);
    *(uint4*)&t[key][d8] = v;
  }
  __syncthreads();
#pragma unroll
  for (int j = 0; j < 2; ++j) {
    int idx = tid + 256 * j;
    int d = idx >> 3, k8 = (idx & 7) << 3;
    ushort tmp[8];
#pragma unroll
    for (int i = 0; i < 8; ++i) tmp[i] = t[k8 + i][d];
    *(uint4*)(vt + (size_t)(h * 64 + d) * S_LEN + c * 64 + k8) = *(const uint4*)tmp;
  }
}

// ---------------- MFMA flash attention: register-pipelined, barrier-free ----------------
// 1792 blocks = 16 heads x 56 items x 2 halves; ONE wave per block, 32 q-rows.
// K/V^T fragments loaded global->register with SW pipeline:
//   V(t) issued at tile top (used after softmax, ~500cyc cover);
//   K(t+1) issued right after QK^T(t) (used next tile, ~700cyc cover).
// No barriers, no K/V LDS; LDS = 4KB epilogue bounce only.
__global__ __launch_bounds__(64) void attn_mfma(
    const ushort* __restrict__ qkv, const ushort* __restrict__ vt,
    ushort* __restrict__ O, ushort* __restrict__ po, float2* __restrict__ pmd,
    const int* __restrict__ icausal)
{
  __shared__ __align__(16) ushort OBL[2048];  // 4KB epilogue bounce

  const int h  = blockIdx.x & 15;
  const int iw = blockIdx.x >> 4;   // 0..111
  const int i  = iw >> 1;           // 0..55 (longest-first item order)
  const int w  = iw & 1;
  const int j = (i < 8) ? (15 - i) : (i < 48) ? (63 - i) : (55 - i);
  int rb4, ns, s;
  if (j < 16)      { rb4 = j; ns = 1; s = 0; }
  else if (j < 32) { rb4 = 16 + ((j - 16) >> 1); ns = 2; s = (j - 16) & 1; }
  else             { int jj = j - 32; int q3 = jj / 3; rb4 = 24 + q3; ns = 3; s = jj - q3 * 3; }

  const int causal = *icausal;
  const int nt = causal ? (rb4 + 1) : (S_LEN / 64);
  const int t0 = s * nt / ns, t1 = (s + 1) * nt / ns;

  const int l = threadIdx.x;
  const int q = l & 31, hi = l >> 5;
  const int q0 = rb4 * 64 + w * 32;   // this wave's first q row
  const int qa = q0 + q;              // this lane's absolute q row

  // Q B-fragments: qf[ks] = Q[qa][16*ks + 8*hi + 0..7]
  short8_t qf[4];
  {
    const ushort* qp = qkv + (size_t)qa * NE + h * HDIM + 8 * hi;
#pragma unroll
    for (int ks = 0; ks < 4; ++ks) {
      union { short8_t v; uint4 u; } uu;
      uu.u = *(const uint4*)(qp + 16 * ks);
      qf[ks] = uu.v;
    }
  }

  // per-lane fragment base pointers
  // K frag (kh half): K[k0 + 32*kh + q][16*ks + 8*hi ..]
  const ushort* kb0 = qkv + (size_t)(t0 * 64 + q) * NE + DMODEL + h * HDIM + 8 * hi;
  const ushort* kb1 = kb0 + (size_t)32 * NE;
  // V^T frag (dh half): Vt[32*dh + q][k0 + 16*ks + 8*hi ..]
  const ushort* vb0 = vt + (size_t)(h * 64 + q) * S_LEN + t0 * 64 + 8 * hi;
  const ushort* vb1 = vb0 + (size_t)32 * S_LEN;

  float m_run = -1e30f, den = 0.f;
  f32x16 oacc[2];
#pragma unroll
  for (int d = 0; d < 2; ++d)
#pragma unroll
    for (int r = 0; r < 16; ++r) oacc[d][r] = 0.f;

  // prologue: prefetch K(t0)
  uint4 kq[8];
#pragma unroll
  for (int ks = 0; ks < 4; ++ks) {
    kq[ks * 2 + 0] = *(const uint4*)(kb0 + 16 * ks);
    kq[ks * 2 + 1] = *(const uint4*)(kb1 + 16 * ks);
  }
  kb0 += (size_t)64 * NE; kb1 += (size_t)64 * NE;

  for (int t = t0; t < t1; ++t) {
    // issue V(t) loads; consumed after softmax (~500 cyc of cover)
    uint4 vq[8];
#pragma unroll
    for (int ks = 0; ks < 4; ++ks) {
      vq[ks * 2 + 0] = *(const uint4*)(vb0 + 16 * ks);
      vq[ks * 2 + 1] = *(const uint4*)(vb1 + 16 * ks);
    }
    vb0 += 64; vb1 += 64;

    // ---- QK^T from prefetched kq: sacc[kh] = S[32*kh + key'][q] ----
    f32x16 sacc[2];
#pragma unroll
    for (int kh = 0; kh < 2; ++kh)
#pragma unroll
      for (int r = 0; r < 16; ++r) sacc[kh][r] = 0.f;
    __builtin_amdgcn_s_setprio(1);
#pragma unroll
    for (int ks = 0; ks < 4; ++ks)
#pragma unroll
      for (int kh = 0; kh < 2; ++kh) {
        union { short8_t v; uint4 u; } ku;
        ku.u = kq[ks * 2 + kh];
        sacc[kh] = __builtin_amdgcn_mfma_f32_32x32x16_bf16(ku.v, qf[ks], sacc[kh], 0, 0, 0);
      }
    __builtin_amdgcn_s_setprio(0);

    // prefetch K(t+1): full tile of cover before next use
    if (t + 1 < t1) {
#pragma unroll
      for (int ks = 0; ks < 4; ++ks) {
        kq[ks * 2 + 0] = *(const uint4*)(kb0 + 16 * ks);
        kq[ks * 2 + 1] = *(const uint4*)(kb1 + 16 * ks);
      }
      kb0 += (size_t)64 * NE; kb1 += (size_t)64 * NE;
    }

    // ---- mask only on the final causal tile (uniform branch) ----
    if (causal && t == rb4) {
      const int k0 = t * 64;
#pragma unroll
      for (int kh = 0; kh < 2; ++kh)
#pragma unroll
        for (int r = 0; r < 16; ++r)
          if (k0 + 32 * kh + (r & 3) + 8 * (r >> 2) + 4 * hi > qa) sacc[kh][r] = -3e38f;
    }

    // ---- row max: 4-partial tree (short dep chains) ----
    float v0 = -3e38f, v1 = -3e38f, v2 = -3e38f, v3 = -3e38f;
#pragma unroll
    for (int kh = 0; kh < 2; ++kh)
#pragma unroll
      for (int r = 0; r < 16; r += 4) {
        v0 = fmaxf(v0, sacc[kh][r + 0]);
        v1 = fmaxf(v1, sacc[kh][r + 1]);
        v2 = fmaxf(v2, sacc[kh][r + 2]);
        v3 = fmaxf(v3, sacc[kh][r + 3]);
      }
    float vmax = fmaxf(fmaxf(v0, v1), fmaxf(v2, v3));
    vmax = fmaxf(vmax, __shfl_xor(vmax, 32));

    // defer-rescale (T13)
    if (__any(vmax > m_run + 44.3614196f)) {   // 8 / C2
      float mn = fmaxf(m_run, vmax);
      float alpha = exp2f((m_run - mn) * C2);
      den *= alpha;
#pragma unroll
      for (int d = 0; d < 2; ++d)
#pragma unroll
        for (int r = 0; r < 16; ++r) oacc[d][r] *= alpha;
      m_run = mn;
    }
    float mc2 = m_run * C2;
    float p0 = 0.f, p1 = 0.f, p2 = 0.f, p3 = 0.f;
#pragma unroll
    for (int kh = 0; kh < 2; ++kh)
#pragma unroll
      for (int r = 0; r < 16; r += 4) {
        float e0 = exp2f(fmaf(sacc[kh][r + 0], C2, -mc2));
        float e1 = exp2f(fmaf(sacc[kh][r + 1], C2, -mc2));
        float e2 = exp2f(fmaf(sacc[kh][r + 2], C2, -mc2));
        float e3 = exp2f(fmaf(sacc[kh][r + 3], C2, -mc2));
        sacc[kh][r + 0] = e0; sacc[kh][r + 1] = e1;
        sacc[kh][r + 2] = e2; sacc[kh][r + 3] = e3;
        p0 += e0; p1 += e1; p2 += e2; p3 += e3;
      }
    float psum = (p0 + p1) + (p2 + p3);
    psum += __shfl_xor(psum, 32);
    den += psum;

    // ---- build PV B-frags: pa[ks][j] = P[16*ks + 8*hi + j][q] ----
    short8_t pa[4];
#pragma unroll
    for (int ks = 0; ks < 4; ++ks) {
      const int blk = ks >> 1, kp = (ks & 1) * 8;
      uint wL0, wL1, wH0, wH1;
      asm("v_cvt_pk_bf16_f32 %0, %1, %2" : "=v"(wL0) : "v"(sacc[blk][kp + 0]), "v"(sacc[blk][kp + 1]));
      asm("v_cvt_pk_bf16_f32 %0, %1, %2" : "=v"(wL1) : "v"(sacc[blk][kp + 2]), "v"(sacc[blk][kp + 3]));
      asm("v_cvt_pk_bf16_f32 %0, %1, %2" : "=v"(wH0) : "v"(sacc[blk][kp + 4]), "v"(sacc[blk][kp + 5]));
      asm("v_cvt_pk_bf16_f32 %0, %1, %2" : "=v"(wH1) : "v"(sacc[blk][kp + 6]), "v"(sacc[blk][kp + 7]));
      uint s0 = hi ? wL0 : wH0, s1 = hi ? wL1 : wH1;
      uint r0 = __shfl_xor(s0, 32), r1 = __shfl_xor(s1, 32);
      union { short8_t v; uint u[4]; } pu;
      pu.u[0] = hi ? r0 : wL0;
      pu.u[1] = hi ? r1 : wL1;
      pu.u[2] = hi ? wH0 : r0;
      pu.u[3] = hi ? wH1 : r1;
      pa[ks] = pu.v;
    }

    // ---- PV from vq (in flight since tile top): oacc[dh] = O^T[32*dh+d'][q] ----
    __builtin_amdgcn_s_setprio(1);
#pragma unroll
    for (int ks = 0; ks < 4; ++ks)
#pragma unroll
      for (int dh = 0; dh < 2; ++dh) {
        union { short8_t v; uint4 u; } vu;
        vu.u = vq[ks * 2 + dh];
        oacc[dh] = __builtin_amdgcn_mfma_f32_32x32x16_bf16(vu.v, pa[ks], oacc[dh], 0, 0, 0);
      }
    __builtin_amdgcn_s_setprio(0);
  }

  // ---- epilogue: bounce O through LDS, coalesced row writes ----
  const int xsw = (q & 7) << 4;
  const float scale = (ns > 1) ? 1.f : (1.f / den);
  char* const Ob = (char*)OBL;
#pragma unroll
  for (int dh = 0; dh < 2; ++dh)
#pragma unroll
    for (int m = 0; m < 4; ++m) {
      uint a0, a1;
      float e0 = oacc[dh][4 * m + 0] * scale, e1 = oacc[dh][4 * m + 1] * scale;
      float e2 = oacc[dh][4 * m + 2] * scale, e3 = oacc[dh][4 * m + 3] * scale;
      asm("v_cvt_pk_bf16_f32 %0, %1, %2" : "=v"(a0) : "v"(e0), "v"(e1));
      asm("v_cvt_pk_bf16_f32 %0, %1, %2" : "=v"(a1) : "v"(e2), "v"(e3));
      uint2 dd; dd.x = a0; dd.y = a1;
      *(uint2*)(Ob + ((q * 128 + 64 * dh + 16 * m + 8 * hi) ^ xsw)) = dd;
    }

  if (ns > 1) {
    const int slot = (rb4 < 24) ? ((rb4 - 16) * 2 + s) : (16 + (rb4 - 24) * 3 + s);
#pragma unroll
    for (int jj = 0; jj < 4; ++jj) {
      int q2 = (l >> 3) + 8 * jj, seg = l & 7;
      uint4 val = *(const uint4*)(Ob + ((q2 * 128 + seg * 16) ^ ((q2 & 7) << 4)));
      *(uint4*)(po + ((size_t)(h * 40 + slot) * 64 + w * 32 + q2) * 64 + seg * 8) = val;
    }
    if (l < 32) pmd[(h * 40 + slot) * 64 + w * 32 + l] = make_float2(m_run, den);
  } else {
#pragma unroll
    for (int jj = 0; jj < 4; ++jj) {
      int q2 = (l >> 3) + 8 * jj, seg = l & 7;
      uint4 val = *(const uint4*)(Ob + ((q2 * 128 + seg * 16) ^ ((q2 & 7) << 4)));
      *(uint4*)(O + (size_t)(q0 + q2) * DMODEL + h * HDIM + seg * 8) = val;
    }
  }
}

// ---------------- combine key-slices for q rows 1024..2047 ----------------
__global__ __launch_bounds__(256) void attn_combine(
    const ushort* __restrict__ po, const float2* __restrict__ pmd,
    ushort* __restrict__ O)
{
  int idx = blockIdx.x * 256 + threadIdx.x;  // 131072
  int d8 = idx & 7;
  int h = (idx >> 3) & 15;
  int r = idx >> 7;                // 0..1023
  int rb4 = 16 + (r >> 6), qi = r & 63;
  int base, ns;
  if (rb4 < 24) { base = (rb4 - 16) * 2; ns = 2; }
  else          { base = 16 + (rb4 - 24) * 3; ns = 3; }

  float2 md0 = pmd[(h * 40 + base + 0) * 64 + qi];
  float2 md1 = pmd[(h * 40 + base + 1) * 64 + qi];
  int i2 = (ns == 3) ? 2 : 0;
  float2 md2 = pmd[(h * 40 + base + i2) * 64 + qi];
  float m = fmaxf(fmaxf(md0.x, md1.x), (ns == 3) ? md2.x : -3e38f);
  float w0 = exp2f((md0.x - m) * C2);
  float w1 = exp2f((md1.x - m) * C2);
  float w2 = (ns == 3) ? exp2f((md2.x - m) * C2) : 0.f;
  float inv = 1.f / (md0.y * w0 + md1.y * w1 + md2.y * w2);

  const ushort* p0 = po + ((size_t)(h * 40 + base + 0) * 64 + qi) * 64 + d8 * 8;
  const ushort* p1 = po + ((size_t)(h * 40 + base + 1) * 64 + qi) * 64 + d8 * 8;
  const ushort* p2 = po + ((size_t)(h * 40 + base + i2) * 64 + qi) * 64 + d8 * 8;
  uint4 a = *(const uint4*)p0, b = *(const uint4*)p1, c = *(const uint4*)p2;
  const ushort* ap = (const ushort*)&a;
  const ushort* bp = (const ushort*)&b;
  const ushort* cp = (const ushort*)&c;
  ushort out8[8];
#pragma unroll
  for (int e = 0; e < 8; ++e)
    out8[e] = f2bf((bf2f(ap[e]) * w0 + bf2f(bp[e]) * w1 + bf2f(cp[e]) * w2) * inv);
  int qq = rb4 * 64 + qi;
  *(uint4*)(O + (size_t)qq * DMODEL + h * HDIM + d8 * 8) = *(const uint4*)out8;
}

// ---------------- launch ----------------
extern "C" void kernel_launch(void* const* d_in, const int* in_sizes, int n_in,
                              void* d_out, int out_size, void* d_ws, size_t ws_size,
                              hipStream_t stream) {
  const float* x     = (const float*)d_in[0];
  const float* w_in  = (const float*)d_in[1];
  const float* w_out = (const float*)d_in[2];
  const int* icausal = (const int*)d_in[3];

  char* ws = (char*)d_ws;
  ushort* xbf    = (ushort*)(ws);                  // 4MB (vt reuses)
  ushort* winbf  = (ushort*)(ws + 4194304);        // 6MB (po/pmd reuse after gemm1)
  ushort* woutbf = (ushort*)(ws + 10485760);       // 2MB
  ushort* qkv    = (ushort*)(ws + 12582912);       // 12MB
  ushort* obuf   = (ushort*)(ws + 25165824);       // 4MB
  ushort* vt     = xbf;                            // 16*64*2048*2B = 4MB
  ushort* po     = winbf;                          // 16*40*64*64*2B = 5.24MB
  float2* pmd    = (float2*)(ws + 4194304 + 5242880);  // 327KB (within winbf 6MB)

  cvt_all<<<6144, 256, 0, stream>>>(x, w_in, w_out, xbf, winbf, woutbf);

  gemm_abt<128, 64, 1><<<16 * 48, 256, 0, stream>>>(xbf, winbf, (void*)qkv, 2048, 3072, 1024);
  rope_kernel<<<8192, 256, 0, stream>>>(qkv);
  transpose_v<<<512, 256, 0, stream>>>(qkv, vt);
  attn_mfma<<<1792, 64, 0, stream>>>(qkv, vt, obuf, po, pmd, icausal);
  attn_combine<<<512, 256, 0, stream>>>(po, pmd, obuf);
  gemm_abt<64, 64, 0><<<32 * 16, 256, 0, stream>>>(obuf, woutbf, d_out, 2048, 1024, 1024);
}

// Round 10
// 96.527 us; speedup vs baseline: 1.1077x; 1.1077x over previous
//
#include <hip/hip_runtime.h>
#include <stdint.h>

#define S_LEN 2048
#define DMODEL 1024
#define NHEAD 16
#define HDIM 64
#define NE 3072
#define C2 0.18033688011112042f  // 0.125 * log2(e)

typedef __attribute__((ext_vector_type(8))) short short8_t;
typedef __attribute__((ext_vector_type(4))) float f32x4;
typedef __attribute__((ext_vector_type(16))) float f32x16;

__device__ __forceinline__ float bf2f(ushort u) {
  union { float f; uint32_t i; } c; c.i = ((uint32_t)u) << 16; return c.f;
}
__device__ __forceinline__ ushort f2bf(float f) {
  union { float f; uint32_t i; } c; c.f = f;
  uint32_t x = c.i;
  return (ushort)((x + 0x7fffu + ((x >> 16) & 1u)) >> 16);
}

__device__ __forceinline__ void gload_lds16(const ushort* g, ushort* l) {
  __builtin_amdgcn_global_load_lds(
      (const __attribute__((address_space(1))) void*)g,
      (__attribute__((address_space(3))) void*)l, 16, 0, 0);
}

// po lives in the dead K/V columns of qkv (after transform_kv copies them out):
// slot p (128B) -> qkv row p>>5, ushort col DMODEL + (p&31)*64
__device__ __forceinline__ ushort* po_ptr(ushort* qkvp, int p) {
  return qkvp + (size_t)(p >> 5) * NE + DMODEL + (p & 31) * 64;
}
__device__ __forceinline__ const ushort* po_cptr(const ushort* qkvp, int p) {
  return qkvp + (size_t)(p >> 5) * NE + DMODEL + (p & 31) * 64;
}

// ---------------- fused fp32 -> bf16 convert (x, w_in, w_out) ----------------
__global__ void cvt_all(const float* __restrict__ x, const float* __restrict__ w_in,
                        const float* __restrict__ w_out,
                        ushort* __restrict__ xbf, ushort* __restrict__ winbf,
                        ushort* __restrict__ woutbf) {
  int i = blockIdx.x * blockDim.x + threadIdx.x;
  const float* src; ushort* dst; int off;
  if (i < 524288)       { src = x;     dst = xbf;    off = i; }
  else if (i < 1310720) { src = w_in;  dst = winbf;  off = i - 524288; }
  else                  { src = w_out; dst = woutbf; off = i - 1310720; }
  float4 v = ((const float4*)src)[off];
  ushort4 o;
  o.x = f2bf(v.x); o.y = f2bf(v.y); o.z = f2bf(v.z); o.w = f2bf(v.w);
  ((ushort4*)dst)[off] = o;
}

// ---------------- bf16 GEMM: C[M][N] = A[M][K] * B[N][K]^T ----------------
template<int BM, int BN, int OUT_BF16>
__global__ __launch_bounds__(256) void gemm_abt(
    const ushort* __restrict__ A, const ushort* __restrict__ B,
    void* __restrict__ Cv, int M, int N, int K)
{
  constexpr int AR = BM / 32;
  constexpr int AC = BN / 32;
  constexpr int NG = (BM + BN) / 16;
  constexpr int PG = NG / 4;
  __shared__ ushort lds[(BM + BN) * 32];

  const int nbn = N / BN;
  const int cpx = gridDim.x >> 3;
  const int bid = blockIdx.x;
  const int swz = (bid & 7) * cpx + (bid >> 3);
  const int bm = swz / nbn;
  const int bn = swz - bm * nbn;
  const int tid = threadIdx.x;
  const int w = tid >> 6, l = tid & 63;
  const int wm = w >> 1, wn = w & 1;
  const int fr = l & 15, fg = l >> 4;

  f32x4 acc[AR][AC];
#pragma unroll
  for (int r = 0; r < AR; ++r)
#pragma unroll
    for (int c = 0; c < AC; ++c) acc[r][c] = (f32x4){0.f, 0.f, 0.f, 0.f};

  const ushort* gsrc[PG];
  ushort* ldst[PG];
#pragma unroll
  for (int i = 0; i < PG; ++i) {
    int c = w + 4 * i;
    if (c < BM / 16) {
      gsrc[i] = A + (size_t)(bm * BM + c * 16 + (l >> 2)) * K + (l & 3) * 8;
      ldst[i] = &lds[c * 512];
    } else {
      int c2 = c - BM / 16;
      gsrc[i] = B + (size_t)(bn * BN + c2 * 16 + (l >> 2)) * K + (l & 3) * 8;
      ldst[i] = &lds[BM * 32 + c2 * 512];
    }
  }

  const ushort* fa = &lds[(wm * (BM / 2) + fr) * 32 + fg * 8];
  const ushort* fb = &lds[BM * 32 + (wn * (BN / 2) + fr) * 32 + fg * 8];

  for (int k0 = 0; k0 < K; k0 += 32) {
    __syncthreads();
#pragma unroll
    for (int i = 0; i < PG; ++i) gload_lds16(gsrc[i] + k0, ldst[i]);
    __syncthreads();

    short8_t af[AR], bfr[AC];
#pragma unroll
    for (int r = 0; r < AR; ++r) {
      union { short8_t v; uint4 q; } u;
      u.q = *(const uint4*)(fa + r * 512);
      af[r] = u.v;
    }
#pragma unroll
    for (int c = 0; c < AC; ++c) {
      union { short8_t v; uint4 q; } u;
      u.q = *(const uint4*)(fb + c * 512);
      bfr[c] = u.v;
    }
    __builtin_amdgcn_s_setprio(1);
#pragma unroll
    for (int r = 0; r < AR; ++r)
#pragma unroll
      for (int c = 0; c < AC; ++c)
        acc[r][c] = __builtin_amdgcn_mfma_f32_16x16x32_bf16(af[r], bfr[c], acc[r][c], 0, 0, 0);
    __builtin_amdgcn_s_setprio(0);
  }

  const int row0 = bm * BM + wm * (BM / 2) + fg * 4;
  const int col0 = bn * BN + wn * (BN / 2) + fr;
#pragma unroll
  for (int r = 0; r < AR; ++r)
#pragma unroll
    for (int c = 0; c < AC; ++c)
#pragma unroll
      for (int j = 0; j < 4; ++j) {
        int row = row0 + r * 16 + j;
        int col = col0 + c * 16;
        if (OUT_BF16)
          ((ushort*)Cv)[(size_t)row * N + col] = f2bf(acc[r][c][j]);
        else
          ((float*)Cv)[(size_t)row * N + col] = acc[r][c][j];
      }
}

// ---------------- RoPE in-place on Q and K sections of qkv ----------------
__global__ void rope_kernel(ushort* __restrict__ qkv) {
  int idx = blockIdx.x * blockDim.x + threadIdx.x;
  int i = idx & 31;
  int hh = (idx >> 5) & (NHEAD - 1);
  int sec = (idx >> 9) & 1;
  int srow = idx >> 10;
  float invf = exp2f((float)i * (-13.287712379549449f / 32.f));
  float ang = (float)srow * invf;
  float sn, c;
  sincosf(ang, &sn, &c);
  size_t base = (size_t)srow * NE + (size_t)sec * DMODEL + hh * HDIM;
  float x1 = bf2f(qkv[base + i]);
  float x2 = bf2f(qkv[base + i + 32]);
  qkv[base + i]      = f2bf(x1 * c - x2 * sn);
  qkv[base + i + 32] = f2bf(x2 * c + x1 * sn);
}

// ---------------- K/V -> fragment-major buffers ----------------
// kfrag[h][t]: chunk c=kh*4+ks, lane l=(hi*32+q):  K[t*64+32*kh+q][16*ks+8*hi+j]
// vfrag[h][t]: chunk c=ks*2+dh, lane l:            V[t*64+16*ks+8*hi+j][32*dh+q]
// Each (h,t) block = 8 chunks x 64 lanes x 8 ushorts = 8KB contiguous.
__global__ __launch_bounds__(256) void transform_kv(
    const ushort* __restrict__ qkv, ushort* __restrict__ kfrag, ushort* __restrict__ vfrag)
{
  __shared__ ushort Kt[64][72];
  __shared__ ushort Vt[64][72];
  const int h = blockIdx.x & 15, t = blockIdx.x >> 4;
  const int tid = threadIdx.x;
#pragma unroll
  for (int it = 0; it < 2; ++it) {
    int idx = tid + 256 * it;
    int key = idx >> 3, d8 = (idx & 7) << 3;
    const ushort* src = qkv + (size_t)(t * 64 + key) * NE + DMODEL + h * HDIM + d8;
    *(uint4*)&Kt[key][d8] = *(const uint4*)src;
    *(uint4*)&Vt[key][d8] = *(const uint4*)(src + DMODEL);
  }
  __syncthreads();
  ushort* kb = kfrag + (size_t)(h * 32 + t) * 4096;
  ushort* vb = vfrag + (size_t)(h * 32 + t) * 4096;
#pragma unroll
  for (int it = 0; it < 2; ++it) {
    int idx = tid + 256 * it;       // 0..511
    int c = idx >> 6, l = idx & 63;
    int q = l & 31, hi = l >> 5;
    int kh = c >> 2, ks = c & 3;
    uint4 v = *(const uint4*)&Kt[32 * kh + q][16 * ks + 8 * hi];
    *(uint4*)(kb + idx * 8) = v;
  }
#pragma unroll
  for (int it = 0; it < 2; ++it) {
    int idx = tid + 256 * it;
    int c = idx >> 6, l = idx & 63;
    int q = l & 31, hi = l >> 5;
    int ks = c >> 1, dh = c & 1;
    ushort tmp[8];
#pragma unroll
    for (int jj = 0; jj < 8; ++jj)
      tmp[jj] = Vt[16 * ks + 8 * hi + jj][32 * dh + q];
    *(uint4*)(vb + idx * 8) = *(const uint4*)tmp;
  }
}

// ---------------- MFMA flash attention: register-pipelined, coalesced frags ----------------
// 1792 blocks = 16 heads x 56 items x 2 halves; ONE wave per block, 32 q-rows.
// K/V^T fragments from fragment-major kfrag/vfrag: each load = contiguous 1KB wave burst.
// V(t) issued at tile top; K(t+1) issued right after QK^T(t). No barriers, 4KB LDS.
__global__ __launch_bounds__(64) void attn_mfma(
    ushort* qkv, const ushort* __restrict__ kfrag, const ushort* __restrict__ vfrag,
    ushort* __restrict__ O, float2* __restrict__ pmd,
    const int* __restrict__ icausal)
{
  __shared__ __align__(16) ushort OBL[2048];  // 4KB epilogue bounce

  const int h  = blockIdx.x & 15;
  const int iw = blockIdx.x >> 4;   // 0..111
  const int i  = iw >> 1;           // 0..55 (longest-first item order)
  const int w  = iw & 1;
  const int j = (i < 8) ? (15 - i) : (i < 48) ? (63 - i) : (55 - i);
  int rb4, ns, s;
  if (j < 16)      { rb4 = j; ns = 1; s = 0; }
  else if (j < 32) { rb4 = 16 + ((j - 16) >> 1); ns = 2; s = (j - 16) & 1; }
  else             { int jj = j - 32; int q3 = jj / 3; rb4 = 24 + q3; ns = 3; s = jj - q3 * 3; }

  const int causal = *icausal;
  const int nt = causal ? (rb4 + 1) : (S_LEN / 64);
  const int t0 = s * nt / ns, t1 = (s + 1) * nt / ns;

  const int l = threadIdx.x;
  const int q = l & 31, hi = l >> 5;
  const int q0 = rb4 * 64 + w * 32;   // this wave's first q row
  const int qa = q0 + q;              // this lane's absolute q row

  // Q B-fragments: qf[ks] = Q[qa][16*ks + 8*hi + 0..7]
  short8_t qf[4];
  {
    const ushort* qp = qkv + (size_t)qa * NE + h * HDIM + 8 * hi;
#pragma unroll
    for (int ks = 0; ks < 4; ++ks) {
      union { short8_t v; uint4 u; } uu;
      uu.u = *(const uint4*)(qp + 16 * ks);
      qf[ks] = uu.v;
    }
  }

  // fragment-major bases (contiguous 8KB per tile, advance 4096 ushorts)
  const ushort* kb = kfrag + (size_t)(h * 32 + t0) * 4096 + l * 8;
  const ushort* vb = vfrag + (size_t)(h * 32 + t0) * 4096 + l * 8;

  float m_run = -1e30f, den = 0.f;
  f32x16 oacc[2];
#pragma unroll
  for (int d = 0; d < 2; ++d)
#pragma unroll
    for (int r = 0; r < 16; ++r) oacc[d][r] = 0.f;

  // prologue: prefetch K(t0)   kq[ks*2+kh] <- chunk (kh*4+ks)
  uint4 kq[8];
#pragma unroll
  for (int ks = 0; ks < 4; ++ks)
#pragma unroll
    for (int kh = 0; kh < 2; ++kh)
      kq[ks * 2 + kh] = *(const uint4*)(kb + (kh * 4 + ks) * 512);
  kb += 4096;

  for (int t = t0; t < t1; ++t) {
    // issue V(t) loads; consumed after softmax   vq[ks*2+dh] <- chunk (ks*2+dh)
    uint4 vq[8];
#pragma unroll
    for (int c = 0; c < 8; ++c)
      vq[c] = *(const uint4*)(vb + c * 512);
    vb += 4096;

    // ---- QK^T from prefetched kq: sacc[kh] = S[32*kh + key'][q] ----
    f32x16 sacc[2];
#pragma unroll
    for (int kh = 0; kh < 2; ++kh)
#pragma unroll
      for (int r = 0; r < 16; ++r) sacc[kh][r] = 0.f;
    __builtin_amdgcn_s_setprio(1);
#pragma unroll
    for (int ks = 0; ks < 4; ++ks)
#pragma unroll
      for (int kh = 0; kh < 2; ++kh) {
        union { short8_t v; uint4 u; } ku;
        ku.u = kq[ks * 2 + kh];
        sacc[kh] = __builtin_amdgcn_mfma_f32_32x32x16_bf16(ku.v, qf[ks], sacc[kh], 0, 0, 0);
      }
    __builtin_amdgcn_s_setprio(0);

    // prefetch K(t+1): full tile of cover before next use
    if (t + 1 < t1) {
#pragma unroll
      for (int ks = 0; ks < 4; ++ks)
#pragma unroll
        for (int kh = 0; kh < 2; ++kh)
          kq[ks * 2 + kh] = *(const uint4*)(kb + (kh * 4 + ks) * 512);
      kb += 4096;
    }

    // ---- mask only on the final causal tile (uniform branch) ----
    if (causal && t == rb4) {
      const int k0 = t * 64;
#pragma unroll
      for (int kh = 0; kh < 2; ++kh)
#pragma unroll
        for (int r = 0; r < 16; ++r)
          if (k0 + 32 * kh + (r & 3) + 8 * (r >> 2) + 4 * hi > qa) sacc[kh][r] = -3e38f;
    }

    // ---- row max: 4-partial tree ----
    float v0 = -3e38f, v1 = -3e38f, v2 = -3e38f, v3 = -3e38f;
#pragma unroll
    for (int kh = 0; kh < 2; ++kh)
#pragma unroll
      for (int r = 0; r < 16; r += 4) {
        v0 = fmaxf(v0, sacc[kh][r + 0]);
        v1 = fmaxf(v1, sacc[kh][r + 1]);
        v2 = fmaxf(v2, sacc[kh][r + 2]);
        v3 = fmaxf(v3, sacc[kh][r + 3]);
      }
    float vmax = fmaxf(fmaxf(v0, v1), fmaxf(v2, v3));
    vmax = fmaxf(vmax, __shfl_xor(vmax, 32));

    // defer-rescale (T13)
    if (__any(vmax > m_run + 44.3614196f)) {   // 8 / C2
      float mn = fmaxf(m_run, vmax);
      float alpha = exp2f((m_run - mn) * C2);
      den *= alpha;
#pragma unroll
      for (int d = 0; d < 2; ++d)
#pragma unroll
        for (int r = 0; r < 16; ++r) oacc[d][r] *= alpha;
      m_run = mn;
    }
    float mc2 = m_run * C2;
    float p0 = 0.f, p1 = 0.f, p2 = 0.f, p3 = 0.f;
#pragma unroll
    for (int kh = 0; kh < 2; ++kh)
#pragma unroll
      for (int r = 0; r < 16; r += 4) {
        float e0 = exp2f(fmaf(sacc[kh][r + 0], C2, -mc2));
        float e1 = exp2f(fmaf(sacc[kh][r + 1], C2, -mc2));
        float e2 = exp2f(fmaf(sacc[kh][r + 2], C2, -mc2));
        float e3 = exp2f(fmaf(sacc[kh][r + 3], C2, -mc2));
        sacc[kh][r + 0] = e0; sacc[kh][r + 1] = e1;
        sacc[kh][r + 2] = e2; sacc[kh][r + 3] = e3;
        p0 += e0; p1 += e1; p2 += e2; p3 += e3;
      }
    float psum = (p0 + p1) + (p2 + p3);
    psum += __shfl_xor(psum, 32);
    den += psum;

    // ---- build PV B-frags: pa[ks][j] = P[16*ks + 8*hi + j][q] ----
    short8_t pa[4];
#pragma unroll
    for (int ks = 0; ks < 4; ++ks) {
      const int blk = ks >> 1, kp = (ks & 1) * 8;
      uint wL0, wL1, wH0, wH1;
      asm("v_cvt_pk_bf16_f32 %0, %1, %2" : "=v"(wL0) : "v"(sacc[blk][kp + 0]), "v"(sacc[blk][kp + 1]));
      asm("v_cvt_pk_bf16_f32 %0, %1, %2" : "=v"(wL1) : "v"(sacc[blk][kp + 2]), "v"(sacc[blk][kp + 3]));
      asm("v_cvt_pk_bf16_f32 %0, %1, %2" : "=v"(wH0) : "v"(sacc[blk][kp + 4]), "v"(sacc[blk][kp + 5]));
      asm("v_cvt_pk_bf16_f32 %0, %1, %2" : "=v"(wH1) : "v"(sacc[blk][kp + 6]), "v"(sacc[blk][kp + 7]));
      uint s0 = hi ? wL0 : wH0, s1 = hi ? wL1 : wH1;
      uint r0 = __shfl_xor(s0, 32), r1 = __shfl_xor(s1, 32);
      union { short8_t v; uint u[4]; } pu;
      pu.u[0] = hi ? r0 : wL0;
      pu.u[1] = hi ? r1 : wL1;
      pu.u[2] = hi ? wH0 : r0;
      pu.u[3] = hi ? wH1 : r1;
      pa[ks] = pu.v;
    }

    // ---- PV from vq: oacc[dh] = O^T[32*dh+d'][q] ----
    __builtin_amdgcn_s_setprio(1);
#pragma unroll
    for (int ks = 0; ks < 4; ++ks)
#pragma unroll
      for (int dh = 0; dh < 2; ++dh) {
        union { short8_t v; uint4 u; } vu;
        vu.u = vq[ks * 2 + dh];
        oacc[dh] = __builtin_amdgcn_mfma_f32_32x32x16_bf16(vu.v, pa[ks], oacc[dh], 0, 0, 0);
      }
    __builtin_amdgcn_s_setprio(0);
  }

  // ---- epilogue: bounce O through LDS, coalesced row writes ----
  const int xsw = (q & 7) << 4;
  const float scale = (ns > 1) ? 1.f : (1.f / den);
  char* const Ob = (char*)OBL;
#pragma unroll
  for (int dh = 0; dh < 2; ++dh)
#pragma unroll
    for (int m = 0; m < 4; ++m) {
      uint a0, a1;
      float e0 = oacc[dh][4 * m + 0] * scale, e1 = oacc[dh][4 * m + 1] * scale;
      float e2 = oacc[dh][4 * m + 2] * scale, e3 = oacc[dh][4 * m + 3] * scale;
      asm("v_cvt_pk_bf16_f32 %0, %1, %2" : "=v"(a0) : "v"(e0), "v"(e1));
      asm("v_cvt_pk_bf16_f32 %0, %1, %2" : "=v"(a1) : "v"(e2), "v"(e3));
      uint2 dd; dd.x = a0; dd.y = a1;
      *(uint2*)(Ob + ((q * 128 + 64 * dh + 16 * m + 8 * hi) ^ xsw)) = dd;
    }

  if (ns > 1) {
    const int slot = (rb4 < 24) ? ((rb4 - 16) * 2 + s) : (16 + (rb4 - 24) * 3 + s);
#pragma unroll
    for (int jj = 0; jj < 4; ++jj) {
      int q2 = (l >> 3) + 8 * jj, seg = l & 7;
      uint4 val = *(const uint4*)(Ob + ((q2 * 128 + seg * 16) ^ ((q2 & 7) << 4)));
      int p = (h * 40 + slot) * 64 + w * 32 + q2;
      *(uint4*)(po_ptr(qkv, p) + seg * 8) = val;
    }
    if (l < 32) pmd[(h * 40 + slot) * 64 + w * 32 + l] = make_float2(m_run, den);
  } else {
#pragma unroll
    for (int jj = 0; jj < 4; ++jj) {
      int q2 = (l >> 3) + 8 * jj, seg = l & 7;
      uint4 val = *(const uint4*)(Ob + ((q2 * 128 + seg * 16) ^ ((q2 & 7) << 4)));
      *(uint4*)(O + (size_t)(q0 + q2) * DMODEL + h * HDIM + seg * 8) = val;
    }
  }
}

// ---------------- combine key-slices for q rows 1024..2047 ----------------
__global__ __launch_bounds__(256) void attn_combine(
    const ushort* __restrict__ qkv, const float2* __restrict__ pmd,
    ushort* __restrict__ O)
{
  int idx = blockIdx.x * 256 + threadIdx.x;  // 131072
  int d8 = idx & 7;
  int h = (idx >> 3) & 15;
  int r = idx >> 7;                // 0..1023
  int rb4 = 16 + (r >> 6), qi = r & 63;
  int base, ns;
  if (rb4 < 24) { base = (rb4 - 16) * 2; ns = 2; }
  else          { base = 16 + (rb4 - 24) * 3; ns = 3; }

  float2 md0 = pmd[(h * 40 + base + 0) * 64 + qi];
  float2 md1 = pmd[(h * 40 + base + 1) * 64 + qi];
  int i2 = (ns == 3) ? 2 : 0;
  float2 md2 = pmd[(h * 40 + base + i2) * 64 + qi];
  float m = fmaxf(fmaxf(md0.x, md1.x), (ns == 3) ? md2.x : -3e38f);
  float w0 = exp2f((md0.x - m) * C2);
  float w1 = exp2f((md1.x - m) * C2);
  float w2 = (ns == 3) ? exp2f((md2.x - m) * C2) : 0.f;
  float inv = 1.f / (md0.y * w0 + md1.y * w1 + md2.y * w2);

  const ushort* p0 = po_cptr(qkv, (h * 40 + base + 0) * 64 + qi) + d8 * 8;
  const ushort* p1 = po_cptr(qkv, (h * 40 + base + 1) * 64 + qi) + d8 * 8;
  const ushort* p2 = po_cptr(qkv, (h * 40 + base + i2) * 64 + qi) + d8 * 8;
  uint4 a = *(const uint4*)p0, b = *(const uint4*)p1, c = *(const uint4*)p2;
  const ushort* ap = (const ushort*)&a;
  const ushort* bp = (const ushort*)&b;
  const ushort* cp = (const ushort*)&c;
  ushort out8[8];
#pragma unroll
  for (int e = 0; e < 8; ++e)
    out8[e] = f2bf((bf2f(ap[e]) * w0 + bf2f(bp[e]) * w1 + bf2f(cp[e]) * w2) * inv);
  int qq = rb4 * 64 + qi;
  *(uint4*)(O + (size_t)qq * DMODEL + h * HDIM + d8 * 8) = *(const uint4*)out8;
}

// ---------------- launch ----------------
extern "C" void kernel_launch(void* const* d_in, const int* in_sizes, int n_in,
                              void* d_out, int out_size, void* d_ws, size_t ws_size,
                              hipStream_t stream) {
  const float* x     = (const float*)d_in[0];
  const float* w_in  = (const float*)d_in[1];
  const float* w_out = (const float*)d_in[2];
  const int* icausal = (const int*)d_in[3];

  char* ws = (char*)d_ws;
  ushort* xbf    = (ushort*)(ws);                  // 4MB (vfrag reuses)
  ushort* winbf  = (ushort*)(ws + 4194304);        // 6MB (kfrag+pmd reuse after gemm1)
  ushort* woutbf = (ushort*)(ws + 10485760);       // 2MB
  ushort* qkv    = (ushort*)(ws + 12582912);       // 12MB (po reuses dead K/V cols)
  ushort* obuf   = (ushort*)(ws + 25165824);       // 4MB
  ushort* vfrag  = xbf;                            // 16*32*4096*2B = 4MB
  ushort* kfrag  = winbf;                          // 4MB
  float2* pmd    = (float2*)(ws + 4194304 + 4194304);  // 327KB (winbf tail)

  cvt_all<<<6144, 256, 0, stream>>>(x, w_in, w_out, xbf, winbf, woutbf);

  gemm_abt<128, 64, 1><<<16 * 48, 256, 0, stream>>>(xbf, winbf, (void*)qkv, 2048, 3072, 1024);
  rope_kernel<<<8192, 256, 0, stream>>>(qkv);
  transform_kv<<<512, 256, 0, stream>>>(qkv, kfrag, vfrag);
  attn_mfma<<<1792, 64, 0, stream>>>(qkv, kfrag, vfrag, obuf, pmd, icausal);
  attn_combine<<<512, 256, 0, stream>>>(qkv, pmd, obuf);
  gemm_abt<64, 64, 0><<<32 * 16, 256, 0, stream>>>(obuf, woutbf, d_out, 2048, 1024, 1024);
}

// Round 11
// 94.359 us; speedup vs baseline: 1.1332x; 1.0230x over previous
//
#include <hip/hip_runtime.h>
#include <stdint.h>

#define S_LEN 2048
#define DMODEL 1024
#define NHEAD 16
#define HDIM 64
#define NE 3072
#define C2 0.18033688011112042f  // 0.125 * log2(e)

typedef __attribute__((ext_vector_type(8))) short short8_t;
typedef __attribute__((ext_vector_type(4))) float f32x4;
typedef __attribute__((ext_vector_type(16))) float f32x16;

__device__ __forceinline__ float bf2f(ushort u) {
  union { float f; uint32_t i; } c; c.i = ((uint32_t)u) << 16; return c.f;
}
__device__ __forceinline__ ushort f2bf(float f) {
  union { float f; uint32_t i; } c; c.f = f;
  uint32_t x = c.i;
  return (ushort)((x + 0x7fffu + ((x >> 16) & 1u)) >> 16);
}

__device__ __forceinline__ void gload_lds16(const ushort* g, ushort* l) {
  __builtin_amdgcn_global_load_lds(
      (const __attribute__((address_space(1))) void*)g,
      (__attribute__((address_space(3))) void*)l, 16, 0, 0);
}

// ---------------- fused fp32 -> bf16 convert (x, w_in, w_out) ----------------
__global__ void cvt_all(const float* __restrict__ x, const float* __restrict__ w_in,
                        const float* __restrict__ w_out,
                        ushort* __restrict__ xbf, ushort* __restrict__ winbf,
                        ushort* __restrict__ woutbf) {
  int i = blockIdx.x * blockDim.x + threadIdx.x;
  const float* src; ushort* dst; int off;
  if (i < 524288)       { src = x;     dst = xbf;    off = i; }
  else if (i < 1310720) { src = w_in;  dst = winbf;  off = i - 524288; }
  else                  { src = w_out; dst = woutbf; off = i - 1310720; }
  float4 v = ((const float4*)src)[off];
  ushort4 o;
  o.x = f2bf(v.x); o.y = f2bf(v.y); o.z = f2bf(v.z); o.w = f2bf(v.w);
  ((ushort4*)dst)[off] = o;
}

// ---------------- bf16 GEMM: C[M][N] = A[M][K] * B[N][K]^T ----------------
template<int BM, int BN, int OUT_BF16>
__global__ __launch_bounds__(256) void gemm_abt(
    const ushort* __restrict__ A, const ushort* __restrict__ B,
    void* __restrict__ Cv, int M, int N, int K)
{
  constexpr int AR = BM / 32;
  constexpr int AC = BN / 32;
  constexpr int NG = (BM + BN) / 16;
  constexpr int PG = NG / 4;
  __shared__ ushort lds[(BM + BN) * 32];

  const int nbn = N / BN;
  const int cpx = gridDim.x >> 3;
  const int bid = blockIdx.x;
  const int swz = (bid & 7) * cpx + (bid >> 3);
  const int bm = swz / nbn;
  const int bn = swz - bm * nbn;
  const int tid = threadIdx.x;
  const int w = tid >> 6, l = tid & 63;
  const int wm = w >> 1, wn = w & 1;
  const int fr = l & 15, fg = l >> 4;

  f32x4 acc[AR][AC];
#pragma unroll
  for (int r = 0; r < AR; ++r)
#pragma unroll
    for (int c = 0; c < AC; ++c) acc[r][c] = (f32x4){0.f, 0.f, 0.f, 0.f};

  const ushort* gsrc[PG];
  ushort* ldst[PG];
#pragma unroll
  for (int i = 0; i < PG; ++i) {
    int c = w + 4 * i;
    if (c < BM / 16) {
      gsrc[i] = A + (size_t)(bm * BM + c * 16 + (l >> 2)) * K + (l & 3) * 8;
      ldst[i] = &lds[c * 512];
    } else {
      int c2 = c - BM / 16;
      gsrc[i] = B + (size_t)(bn * BN + c2 * 16 + (l >> 2)) * K + (l & 3) * 8;
      ldst[i] = &lds[BM * 32 + c2 * 512];
    }
  }

  const ushort* fa = &lds[(wm * (BM / 2) + fr) * 32 + fg * 8];
  const ushort* fb = &lds[BM * 32 + (wn * (BN / 2) + fr) * 32 + fg * 8];

  for (int k0 = 0; k0 < K; k0 += 32) {
    __syncthreads();
#pragma unroll
    for (int i = 0; i < PG; ++i) gload_lds16(gsrc[i] + k0, ldst[i]);
    __syncthreads();

    short8_t af[AR], bfr[AC];
#pragma unroll
    for (int r = 0; r < AR; ++r) {
      union { short8_t v; uint4 q; } u;
      u.q = *(const uint4*)(fa + r * 512);
      af[r] = u.v;
    }
#pragma unroll
    for (int c = 0; c < AC; ++c) {
      union { short8_t v; uint4 q; } u;
      u.q = *(const uint4*)(fb + c * 512);
      bfr[c] = u.v;
    }
    __builtin_amdgcn_s_setprio(1);
#pragma unroll
    for (int r = 0; r < AR; ++r)
#pragma unroll
      for (int c = 0; c < AC; ++c)
        acc[r][c] = __builtin_amdgcn_mfma_f32_16x16x32_bf16(af[r], bfr[c], acc[r][c], 0, 0, 0);
    __builtin_amdgcn_s_setprio(0);
  }

  const int row0 = bm * BM + wm * (BM / 2) + fg * 4;
  const int col0 = bn * BN + wn * (BN / 2) + fr;
#pragma unroll
  for (int r = 0; r < AR; ++r)
#pragma unroll
    for (int c = 0; c < AC; ++c)
#pragma unroll
      for (int j = 0; j < 4; ++j) {
        int row = row0 + r * 16 + j;
        int col = col0 + c * 16;
        if (OUT_BF16)
          ((ushort*)Cv)[(size_t)row * N + col] = f2bf(acc[r][c][j]);
        else
          ((float*)Cv)[(size_t)row * N + col] = acc[r][c][j];
      }
}

// ---------------- RoPE in-place on Q and K sections of qkv ----------------
__global__ void rope_kernel(ushort* __restrict__ qkv) {
  int idx = blockIdx.x * blockDim.x + threadIdx.x;
  int i = idx & 31;
  int hh = (idx >> 5) & (NHEAD - 1);
  int sec = (idx >> 9) & 1;
  int srow = idx >> 10;
  float invf = exp2f((float)i * (-13.287712379549449f / 32.f));
  float ang = (float)srow * invf;
  float sn, c;
  sincosf(ang, &sn, &c);
  size_t base = (size_t)srow * NE + (size_t)sec * DMODEL + hh * HDIM;
  float x1 = bf2f(qkv[base + i]);
  float x2 = bf2f(qkv[base + i + 32]);
  qkv[base + i]      = f2bf(x1 * c - x2 * sn);
  qkv[base + i + 32] = f2bf(x2 * c + x1 * sn);
}

// ---------------- K/V -> fragment-major buffers ----------------
// kfrag[h][t]: chunk c=kh*4+ks, lane l=(hi*32+q):  K[t*64+32*kh+q][16*ks+8*hi+j]
// vfrag[h][t]: chunk c=ks*2+dh, lane l:            V[t*64+16*ks+8*hi+j][32*dh+q]
__global__ __launch_bounds__(256) void transform_kv(
    const ushort* __restrict__ qkv, ushort* __restrict__ kfrag, ushort* __restrict__ vfrag)
{
  __shared__ ushort Kt[64][72];
  __shared__ ushort Vt[64][72];
  const int h = blockIdx.x & 15, t = blockIdx.x >> 4;
  const int tid = threadIdx.x;
#pragma unroll
  for (int it = 0; it < 2; ++it) {
    int idx = tid + 256 * it;
    int key = idx >> 3, d8 = (idx & 7) << 3;
    const ushort* src = qkv + (size_t)(t * 64 + key) * NE + DMODEL + h * HDIM + d8;
    *(uint4*)&Kt[key][d8] = *(const uint4*)src;
    *(uint4*)&Vt[key][d8] = *(const uint4*)(src + DMODEL);
  }
  __syncthreads();
  ushort* kb = kfrag + (size_t)(h * 32 + t) * 4096;
  ushort* vb = vfrag + (size_t)(h * 32 + t) * 4096;
#pragma unroll
  for (int it = 0; it < 2; ++it) {
    int idx = tid + 256 * it;       // 0..511
    int c = idx >> 6, l = idx & 63;
    int q = l & 31, hi = l >> 5;
    int kh = c >> 2, ks = c & 3;
    uint4 v = *(const uint4*)&Kt[32 * kh + q][16 * ks + 8 * hi];
    *(uint4*)(kb + idx * 8) = v;
  }
#pragma unroll
  for (int it = 0; it < 2; ++it) {
    int idx = tid + 256 * it;
    int c = idx >> 6, l = idx & 63;
    int q = l & 31, hi = l >> 5;
    int ks = c >> 1, dh = c & 1;
    ushort tmp[8];
#pragma unroll
    for (int jj = 0; jj < 8; ++jj)
      tmp[jj] = Vt[16 * ks + 8 * hi + jj][32 * dh + q];
    *(uint4*)(vb + idx * 8) = *(const uint4*)tmp;
  }
}

// ---------------- MFMA flash attention: in-block split-K, 4 independent waves ----------------
// 1024 blocks = 16 heads x 64 q-tiles (32 rows). 4 waves split the nt key-tiles
// (contiguous quarters, <=8 tiles each), each running the register-pipelined
// loop with NO barriers; merge of the 4 partials happens in LDS at the end.
// Per-CU balance: qt in {g, 63-g, 31-g, 32+g} across the 4 grid quarters -> sum(nt)=67 const.
__global__ __launch_bounds__(256) void attn_mfma(
    const ushort* __restrict__ qkv, const ushort* __restrict__ kfrag,
    const ushort* __restrict__ vfrag, ushort* __restrict__ O,
    const int* __restrict__ icausal)
{
  __shared__ ushort obf[4][32][68];   // per-wave unnormalized O^T, bf16, pad-68
  __shared__ float2 mdl[4][32];       // per-wave {m, den}

  const int h = blockIdx.x & 15;
  const int i = blockIdx.x >> 4;      // 0..63
  const int g = i & 15, k = i >> 4;   // k = grid quarter (CU stride class)
  const int qt = (k == 0) ? g : (k == 1) ? (63 - g) : (k == 2) ? (31 - g) : (32 + g);

  const int causal = *icausal;
  const int nt = causal ? ((qt >> 1) + 1) : (S_LEN / 64);

  const int tid = threadIdx.x;
  const int w = tid >> 6, l = tid & 63;
  const int q = l & 31, hi = l >> 5;
  const int q0 = qt * 32;
  const int qa = q0 + q;
  const int t0 = w * nt / 4, t1 = (w + 1) * nt / 4;

  // Q B-fragments: qf[ks] = Q[qa][16*ks + 8*hi + 0..7]
  short8_t qf[4];
  {
    const ushort* qp = qkv + (size_t)qa * NE + h * HDIM + 8 * hi;
#pragma unroll
    for (int ks = 0; ks < 4; ++ks) {
      union { short8_t v; uint4 u; } uu;
      uu.u = *(const uint4*)(qp + 16 * ks);
      qf[ks] = uu.v;
    }
  }

  const ushort* kb = kfrag + (size_t)(h * 32 + t0) * 4096 + l * 8;
  const ushort* vb = vfrag + (size_t)(h * 32 + t0) * 4096 + l * 8;

  float m_run = -1e30f, den = 0.f;
  f32x16 oacc[2];
#pragma unroll
  for (int d = 0; d < 2; ++d)
#pragma unroll
    for (int r = 0; r < 16; ++r) oacc[d][r] = 0.f;

  if (t0 < t1) {
    // prologue: prefetch K(t0)
    uint4 kq[8];
#pragma unroll
    for (int ks = 0; ks < 4; ++ks)
#pragma unroll
      for (int kh = 0; kh < 2; ++kh)
        kq[ks * 2 + kh] = *(const uint4*)(kb + (kh * 4 + ks) * 512);
    kb += 4096;

    for (int t = t0; t < t1; ++t) {
      // issue V(t) loads; consumed after softmax
      uint4 vq[8];
#pragma unroll
      for (int c = 0; c < 8; ++c)
        vq[c] = *(const uint4*)(vb + c * 512);
      vb += 4096;

      // ---- QK^T: sacc[kh] = S[32*kh + key'][q] ----
      f32x16 sacc[2];
#pragma unroll
      for (int kh = 0; kh < 2; ++kh)
#pragma unroll
        for (int r = 0; r < 16; ++r) sacc[kh][r] = 0.f;
      __builtin_amdgcn_s_setprio(1);
#pragma unroll
      for (int ks = 0; ks < 4; ++ks)
#pragma unroll
        for (int kh = 0; kh < 2; ++kh) {
          union { short8_t v; uint4 u; } ku;
          ku.u = kq[ks * 2 + kh];
          sacc[kh] = __builtin_amdgcn_mfma_f32_32x32x16_bf16(ku.v, qf[ks], sacc[kh], 0, 0, 0);
        }
      __builtin_amdgcn_s_setprio(0);

      // prefetch K(t+1)
      if (t + 1 < t1) {
#pragma unroll
        for (int ks = 0; ks < 4; ++ks)
#pragma unroll
          for (int kh = 0; kh < 2; ++kh)
            kq[ks * 2 + kh] = *(const uint4*)(kb + (kh * 4 + ks) * 512);
        kb += 4096;
      }

      // ---- causal mask only on the diagonal (last) tile ----
      if (causal && t == nt - 1) {
        const int k0 = t * 64;
#pragma unroll
        for (int kh = 0; kh < 2; ++kh)
#pragma unroll
          for (int r = 0; r < 16; ++r)
            if (k0 + 32 * kh + (r & 3) + 8 * (r >> 2) + 4 * hi > qa) sacc[kh][r] = -3e38f;
      }

      // ---- row max: 4-partial tree ----
      float v0 = -3e38f, v1 = -3e38f, v2 = -3e38f, v3 = -3e38f;
#pragma unroll
      for (int kh = 0; kh < 2; ++kh)
#pragma unroll
        for (int r = 0; r < 16; r += 4) {
          v0 = fmaxf(v0, sacc[kh][r + 0]);
          v1 = fmaxf(v1, sacc[kh][r + 1]);
          v2 = fmaxf(v2, sacc[kh][r + 2]);
          v3 = fmaxf(v3, sacc[kh][r + 3]);
        }
      float vmax = fmaxf(fmaxf(v0, v1), fmaxf(v2, v3));
      vmax = fmaxf(vmax, __shfl_xor(vmax, 32));

      // defer-rescale (T13)
      if (__any(vmax > m_run + 44.3614196f)) {   // 8 / C2
        float mn = fmaxf(m_run, vmax);
        float alpha = exp2f((m_run - mn) * C2);
        den *= alpha;
#pragma unroll
        for (int d = 0; d < 2; ++d)
#pragma unroll
          for (int r = 0; r < 16; ++r) oacc[d][r] *= alpha;
        m_run = mn;
      }
      float mc2 = m_run * C2;
      float p0 = 0.f, p1 = 0.f, p2 = 0.f, p3 = 0.f;
#pragma unroll
      for (int kh = 0; kh < 2; ++kh)
#pragma unroll
        for (int r = 0; r < 16; r += 4) {
          float e0 = exp2f(fmaf(sacc[kh][r + 0], C2, -mc2));
          float e1 = exp2f(fmaf(sacc[kh][r + 1], C2, -mc2));
          float e2 = exp2f(fmaf(sacc[kh][r + 2], C2, -mc2));
          float e3 = exp2f(fmaf(sacc[kh][r + 3], C2, -mc2));
          sacc[kh][r + 0] = e0; sacc[kh][r + 1] = e1;
          sacc[kh][r + 2] = e2; sacc[kh][r + 3] = e3;
          p0 += e0; p1 += e1; p2 += e2; p3 += e3;
        }
      float psum = (p0 + p1) + (p2 + p3);
      psum += __shfl_xor(psum, 32);
      den += psum;

      // ---- build PV B-frags: pa[ks][j] = P[16*ks + 8*hi + j][q] ----
      short8_t pa[4];
#pragma unroll
      for (int ks = 0; ks < 4; ++ks) {
        const int blk = ks >> 1, kp = (ks & 1) * 8;
        uint wL0, wL1, wH0, wH1;
        asm("v_cvt_pk_bf16_f32 %0, %1, %2" : "=v"(wL0) : "v"(sacc[blk][kp + 0]), "v"(sacc[blk][kp + 1]));
        asm("v_cvt_pk_bf16_f32 %0, %1, %2" : "=v"(wL1) : "v"(sacc[blk][kp + 2]), "v"(sacc[blk][kp + 3]));
        asm("v_cvt_pk_bf16_f32 %0, %1, %2" : "=v"(wH0) : "v"(sacc[blk][kp + 4]), "v"(sacc[blk][kp + 5]));
        asm("v_cvt_pk_bf16_f32 %0, %1, %2" : "=v"(wH1) : "v"(sacc[blk][kp + 6]), "v"(sacc[blk][kp + 7]));
        uint s0 = hi ? wL0 : wH0, s1 = hi ? wL1 : wH1;
        uint r0 = __shfl_xor(s0, 32), r1 = __shfl_xor(s1, 32);
        union { short8_t v; uint u[4]; } pu;
        pu.u[0] = hi ? r0 : wL0;
        pu.u[1] = hi ? r1 : wL1;
        pu.u[2] = hi ? wH0 : r0;
        pu.u[3] = hi ? wH1 : r1;
        pa[ks] = pu.v;
      }

      // ---- PV: oacc[dh] = O^T[32*dh + d'][q] ----
      __builtin_amdgcn_s_setprio(1);
#pragma unroll
      for (int ks = 0; ks < 4; ++ks)
#pragma unroll
        for (int dh = 0; dh < 2; ++dh) {
          union { short8_t v; uint4 u; } vu;
          vu.u = vq[ks * 2 + dh];
          oacc[dh] = __builtin_amdgcn_mfma_f32_32x32x16_bf16(vu.v, pa[ks], oacc[dh], 0, 0, 0);
        }
      __builtin_amdgcn_s_setprio(0);
    }
  }

  // ---- deposit this wave's partial into LDS ----
  // d = 32*dh + 8*rq + 4*hi + j  for oacc[dh][4*rq + j]
#pragma unroll
  for (int dh = 0; dh < 2; ++dh)
#pragma unroll
    for (int rq = 0; rq < 4; ++rq) {
      uint a0, a1;
      asm("v_cvt_pk_bf16_f32 %0, %1, %2" : "=v"(a0) : "v"(oacc[dh][4 * rq + 0]), "v"(oacc[dh][4 * rq + 1]));
      asm("v_cvt_pk_bf16_f32 %0, %1, %2" : "=v"(a1) : "v"(oacc[dh][4 * rq + 2]), "v"(oacc[dh][4 * rq + 3]));
      uint2 dd; dd.x = a0; dd.y = a1;
      *(uint2*)&obf[w][q][32 * dh + 8 * rq + 4 * hi] = dd;
    }
  if (hi == 0) mdl[w][q] = make_float2(m_run, den);
  __syncthreads();

  // ---- 4-way merge: thread (qq = tid>>3, d8 = tid&7) handles 8 d-elements ----
  {
    const int qq = tid >> 3, d8 = tid & 7;
    float2 md0 = mdl[0][qq], md1 = mdl[1][qq], md2 = mdl[2][qq], md3 = mdl[3][qq];
    float mt = fmaxf(fmaxf(md0.x, md1.x), fmaxf(md2.x, md3.x));
    float w0 = exp2f((md0.x - mt) * C2);
    float w1 = exp2f((md1.x - mt) * C2);
    float w2 = exp2f((md2.x - mt) * C2);
    float w3 = exp2f((md3.x - mt) * C2);
    float inv = 1.f / (md0.y * w0 + md1.y * w1 + md2.y * w2 + md3.y * w3);

    uint4 a = *(const uint4*)&obf[0][qq][d8 * 8];
    uint4 b = *(const uint4*)&obf[1][qq][d8 * 8];
    uint4 c = *(const uint4*)&obf[2][qq][d8 * 8];
    uint4 d = *(const uint4*)&obf[3][qq][d8 * 8];
    const ushort* ap = (const ushort*)&a;
    const ushort* bp = (const ushort*)&b;
    const ushort* cp = (const ushort*)&c;
    const ushort* dp = (const ushort*)&d;
    ushort out8[8];
#pragma unroll
    for (int e = 0; e < 8; ++e) {
      float acc = bf2f(ap[e]) * w0 + bf2f(bp[e]) * w1 + bf2f(cp[e]) * w2 + bf2f(dp[e]) * w3;
      out8[e] = f2bf(acc * inv);
    }
    *(uint4*)(O + (size_t)(q0 + qq) * DMODEL + h * HDIM + d8 * 8) = *(const uint4*)out8;
  }
}

// ---------------- launch ----------------
extern "C" void kernel_launch(void* const* d_in, const int* in_sizes, int n_in,
                              void* d_out, int out_size, void* d_ws, size_t ws_size,
                              hipStream_t stream) {
  const float* x     = (const float*)d_in[0];
  const float* w_in  = (const float*)d_in[1];
  const float* w_out = (const float*)d_in[2];
  const int* icausal = (const int*)d_in[3];

  char* ws = (char*)d_ws;
  ushort* xbf    = (ushort*)(ws);                  // 4MB (vfrag reuses)
  ushort* winbf  = (ushort*)(ws + 4194304);        // 6MB (kfrag reuses after gemm1)
  ushort* woutbf = (ushort*)(ws + 10485760);       // 2MB
  ushort* qkv    = (ushort*)(ws + 12582912);       // 12MB
  ushort* obuf   = (ushort*)(ws + 25165824);       // 4MB
  ushort* vfrag  = xbf;                            // 16*32*4096*2B = 4MB
  ushort* kfrag  = winbf;                          // 4MB

  cvt_all<<<6144, 256, 0, stream>>>(x, w_in, w_out, xbf, winbf, woutbf);

  gemm_abt<128, 64, 1><<<16 * 48, 256, 0, stream>>>(xbf, winbf, (void*)qkv, 2048, 3072, 1024);
  rope_kernel<<<8192, 256, 0, stream>>>(qkv);
  transform_kv<<<512, 256, 0, stream>>>(qkv, kfrag, vfrag);
  attn_mfma<<<1024, 256, 0, stream>>>(qkv, kfrag, vfrag, obuf, icausal);
  gemm_abt<64, 64, 0><<<32 * 16, 256, 0, stream>>>(obuf, woutbf, d_out, 2048, 1024, 1024);
}

// Round 12
// 89.601 us; speedup vs baseline: 1.1933x; 1.0531x over previous
//
#include <hip/hip_runtime.h>
#include <stdint.h>

#define S_LEN 2048
#define DMODEL 1024
#define NHEAD 16
#define HDIM 64
#define NE 3072
#define C2 0.18033688011112042f  // 0.125 * log2(e)
#define RINV (-13.287712379549449f / 32.f)  // -log2(10000)/32

typedef __attribute__((ext_vector_type(8))) short short8_t;
typedef __attribute__((ext_vector_type(4))) float f32x4;
typedef __attribute__((ext_vector_type(16))) float f32x16;

__device__ __forceinline__ float bf2f(ushort u) {
  union { float f; uint32_t i; } c; c.i = ((uint32_t)u) << 16; return c.f;
}
__device__ __forceinline__ ushort f2bf(float f) {
  union { float f; uint32_t i; } c; c.f = f;
  uint32_t x = c.i;
  return (ushort)((x + 0x7fffu + ((x >> 16) & 1u)) >> 16);
}

__device__ __forceinline__ void gload_lds16(const ushort* g, ushort* l) {
  __builtin_amdgcn_global_load_lds(
      (const __attribute__((address_space(1))) void*)g,
      (__attribute__((address_space(3))) void*)l, 16, 0, 0);
}

// ---------------- fused fp32 -> bf16 convert (x, w_in, w_out) ----------------
__global__ void cvt_all(const float* __restrict__ x, const float* __restrict__ w_in,
                        const float* __restrict__ w_out,
                        ushort* __restrict__ xbf, ushort* __restrict__ winbf,
                        ushort* __restrict__ woutbf) {
  int i = blockIdx.x * blockDim.x + threadIdx.x;
  const float* src; ushort* dst; int off;
  if (i < 524288)       { src = x;     dst = xbf;    off = i; }
  else if (i < 1310720) { src = w_in;  dst = winbf;  off = i - 524288; }
  else                  { src = w_out; dst = woutbf; off = i - 1310720; }
  float4 v = ((const float4*)src)[off];
  ushort4 o;
  o.x = f2bf(v.x); o.y = f2bf(v.y); o.z = f2bf(v.z); o.w = f2bf(v.w);
  ((ushort4*)dst)[off] = o;
}

// ---------------- bf16 GEMM: C[M][N] = A[M][K] * B[N][K]^T ----------------
template<int BM, int BN, int OUT_BF16>
__global__ __launch_bounds__(256) void gemm_abt(
    const ushort* __restrict__ A, const ushort* __restrict__ B,
    void* __restrict__ Cv, int M, int N, int K)
{
  constexpr int AR = BM / 32;
  constexpr int AC = BN / 32;
  constexpr int NG = (BM + BN) / 16;
  constexpr int PG = NG / 4;
  __shared__ ushort lds[(BM + BN) * 32];

  const int nbn = N / BN;
  const int cpx = gridDim.x >> 3;
  const int bid = blockIdx.x;
  const int swz = (bid & 7) * cpx + (bid >> 3);
  const int bm = swz / nbn;
  const int bn = swz - bm * nbn;
  const int tid = threadIdx.x;
  const int w = tid >> 6, l = tid & 63;
  const int wm = w >> 1, wn = w & 1;
  const int fr = l & 15, fg = l >> 4;

  f32x4 acc[AR][AC];
#pragma unroll
  for (int r = 0; r < AR; ++r)
#pragma unroll
    for (int c = 0; c < AC; ++c) acc[r][c] = (f32x4){0.f, 0.f, 0.f, 0.f};

  const ushort* gsrc[PG];
  ushort* ldst[PG];
#pragma unroll
  for (int i = 0; i < PG; ++i) {
    int c = w + 4 * i;
    if (c < BM / 16) {
      gsrc[i] = A + (size_t)(bm * BM + c * 16 + (l >> 2)) * K + (l & 3) * 8;
      ldst[i] = &lds[c * 512];
    } else {
      int c2 = c - BM / 16;
      gsrc[i] = B + (size_t)(bn * BN + c2 * 16 + (l >> 2)) * K + (l & 3) * 8;
      ldst[i] = &lds[BM * 32 + c2 * 512];
    }
  }

  const ushort* fa = &lds[(wm * (BM / 2) + fr) * 32 + fg * 8];
  const ushort* fb = &lds[BM * 32 + (wn * (BN / 2) + fr) * 32 + fg * 8];

  for (int k0 = 0; k0 < K; k0 += 32) {
    __syncthreads();
#pragma unroll
    for (int i = 0; i < PG; ++i) gload_lds16(gsrc[i] + k0, ldst[i]);
    __syncthreads();

    short8_t af[AR], bfr[AC];
#pragma unroll
    for (int r = 0; r < AR; ++r) {
      union { short8_t v; uint4 q; } u;
      u.q = *(const uint4*)(fa + r * 512);
      af[r] = u.v;
    }
#pragma unroll
    for (int c = 0; c < AC; ++c) {
      union { short8_t v; uint4 q; } u;
      u.q = *(const uint4*)(fb + c * 512);
      bfr[c] = u.v;
    }
    __builtin_amdgcn_s_setprio(1);
#pragma unroll
    for (int r = 0; r < AR; ++r)
#pragma unroll
      for (int c = 0; c < AC; ++c)
        acc[r][c] = __builtin_amdgcn_mfma_f32_16x16x32_bf16(af[r], bfr[c], acc[r][c], 0, 0, 0);
    __builtin_amdgcn_s_setprio(0);
  }

  const int row0 = bm * BM + wm * (BM / 2) + fg * 4;
  const int col0 = bn * BN + wn * (BN / 2) + fr;
#pragma unroll
  for (int r = 0; r < AR; ++r)
#pragma unroll
    for (int c = 0; c < AC; ++c)
#pragma unroll
      for (int j = 0; j < 4; ++j) {
        int row = row0 + r * 16 + j;
        int col = col0 + c * 16;
        if (OUT_BF16)
          ((ushort*)Cv)[(size_t)row * N + col] = f2bf(acc[r][c][j]);
        else
          ((float*)Cv)[(size_t)row * N + col] = acc[r][c][j];
      }
}

// ---------------- K/V -> fragment-major buffers, K-RoPE fused in LDS ----------------
// kfrag[h][t]: chunk c=kh*4+ks, lane l=(hi*32+q):  K[t*64+32*kh+q][16*ks+8*hi+j] (roped)
// vfrag[h][t]: chunk c=ks*2+dh, lane l:            V[t*64+16*ks+8*hi+j][32*dh+q]
__global__ __launch_bounds__(256) void transform_kv(
    const ushort* __restrict__ qkv, ushort* __restrict__ kfrag, ushort* __restrict__ vfrag)
{
  __shared__ ushort Kt[64][72];
  __shared__ ushort Vt[64][72];
  const int h = blockIdx.x & 15, t = blockIdx.x >> 4;
  const int tid = threadIdx.x;
#pragma unroll
  for (int it = 0; it < 2; ++it) {
    int idx = tid + 256 * it;
    int key = idx >> 3, d8 = (idx & 7) << 3;
    const ushort* src = qkv + (size_t)(t * 64 + key) * NE + DMODEL + h * HDIM + d8;
    *(uint4*)&Kt[key][d8] = *(const uint4*)src;
    *(uint4*)&Vt[key][d8] = *(const uint4*)(src + DMODEL);
  }
  __syncthreads();

  // --- RoPE on K in LDS: pair (i, i+32) per key; 8 keys per thread ---
  {
    const int i = tid & 31;
    const int k8 = (tid >> 5) * 8;
    float invf = exp2f((float)i * RINV);
#pragma unroll
    for (int kk = 0; kk < 8; ++kk) {
      int key = k8 + kk;
      float sn, cs;
      sincosf((float)(t * 64 + key) * invf, &sn, &cs);
      float x1 = bf2f(Kt[key][i]), x2 = bf2f(Kt[key][i + 32]);
      Kt[key][i]      = f2bf(x1 * cs - x2 * sn);
      Kt[key][i + 32] = f2bf(x2 * cs + x1 * sn);
    }
  }
  __syncthreads();

  ushort* kb = kfrag + (size_t)(h * 32 + t) * 4096;
  ushort* vb = vfrag + (size_t)(h * 32 + t) * 4096;
#pragma unroll
  for (int it = 0; it < 2; ++it) {
    int idx = tid + 256 * it;       // 0..511
    int c = idx >> 6, l = idx & 63;
    int q = l & 31, hi = l >> 5;
    int kh = c >> 2, ks = c & 3;
    uint4 v = *(const uint4*)&Kt[32 * kh + q][16 * ks + 8 * hi];
    *(uint4*)(kb + idx * 8) = v;
  }
#pragma unroll
  for (int it = 0; it < 2; ++it) {
    int idx = tid + 256 * it;
    int c = idx >> 6, l = idx & 63;
    int q = l & 31, hi = l >> 5;
    int ks = c >> 1, dh = c & 1;
    ushort tmp[8];
#pragma unroll
    for (int jj = 0; jj < 8; ++jj)
      tmp[jj] = Vt[16 * ks + 8 * hi + jj][32 * dh + q];
    *(uint4*)(vb + idx * 8) = *(const uint4*)tmp;
  }
}

// ---------------- MFMA flash attention: in-block split-K, Q-RoPE in-register ----------------
// 1024 blocks = 16 heads x 64 q-tiles (32 rows). 4 waves split the nt key-tiles
// (contiguous quarters), each running the register-pipelined loop with NO
// barriers; 4-way merge in LDS at the end.
__global__ __launch_bounds__(256) void attn_mfma(
    const ushort* __restrict__ qkv, const ushort* __restrict__ kfrag,
    const ushort* __restrict__ vfrag, ushort* __restrict__ O,
    const int* __restrict__ icausal)
{
  __shared__ ushort obf[4][32][68];   // per-wave unnormalized O^T, bf16, pad-68
  __shared__ float2 mdl[4][32];       // per-wave {m, den}

  const int h = blockIdx.x & 15;
  const int i = blockIdx.x >> 4;      // 0..63
  const int g = i & 15, k = i >> 4;   // k = grid quarter (CU stride class)
  const int qt = (k == 0) ? g : (k == 1) ? (63 - g) : (k == 2) ? (31 - g) : (32 + g);

  const int causal = *icausal;
  const int nt = causal ? ((qt >> 1) + 1) : (S_LEN / 64);

  const int tid = threadIdx.x;
  const int w = tid >> 6, l = tid & 63;
  const int q = l & 31, hi = l >> 5;
  const int q0 = qt * 32;
  const int qa = q0 + q;
  const int t0 = w * nt / 4, t1 = (w + 1) * nt / 4;

  // Q B-fragments + in-register RoPE: pairs (qf[0],qf[2]) and (qf[1],qf[3])
  short8_t qf[4];
  {
    const ushort* qp = qkv + (size_t)qa * NE + h * HDIM + 8 * hi;
#pragma unroll
    for (int ks = 0; ks < 4; ++ks) {
      union { short8_t v; uint4 u; } uu;
      uu.u = *(const uint4*)(qp + 16 * ks);
      qf[ks] = uu.v;
    }
    union { short8_t v; ushort u[8]; } a0, a1, b0, b1;
    a0.v = qf[0]; a1.v = qf[1]; b0.v = qf[2]; b1.v = qf[3];
#pragma unroll
    for (int j = 0; j < 8; ++j) {
      {
        float invf = exp2f((float)(8 * hi + j) * RINV);        // i = d, d = 8*hi+j
        float sn, cs; sincosf((float)qa * invf, &sn, &cs);
        float x1 = bf2f(a0.u[j]), x2 = bf2f(b0.u[j]);
        a0.u[j] = f2bf(x1 * cs - x2 * sn);
        b0.u[j] = f2bf(x2 * cs + x1 * sn);
      }
      {
        float invf = exp2f((float)(16 + 8 * hi + j) * RINV);   // i = d, d = 16+8*hi+j
        float sn, cs; sincosf((float)qa * invf, &sn, &cs);
        float x1 = bf2f(a1.u[j]), x2 = bf2f(b1.u[j]);
        a1.u[j] = f2bf(x1 * cs - x2 * sn);
        b1.u[j] = f2bf(x2 * cs + x1 * sn);
      }
    }
    qf[0] = a0.v; qf[1] = a1.v; qf[2] = b0.v; qf[3] = b1.v;
  }

  const ushort* kb = kfrag + (size_t)(h * 32 + t0) * 4096 + l * 8;
  const ushort* vb = vfrag + (size_t)(h * 32 + t0) * 4096 + l * 8;

  float m_run = -1e30f, den = 0.f;
  f32x16 oacc[2];
#pragma unroll
  for (int d = 0; d < 2; ++d)
#pragma unroll
    for (int r = 0; r < 16; ++r) oacc[d][r] = 0.f;

  if (t0 < t1) {
    // prologue: prefetch K(t0)
    uint4 kq[8];
#pragma unroll
    for (int ks = 0; ks < 4; ++ks)
#pragma unroll
      for (int kh = 0; kh < 2; ++kh)
        kq[ks * 2 + kh] = *(const uint4*)(kb + (kh * 4 + ks) * 512);
    kb += 4096;

    for (int t = t0; t < t1; ++t) {
      // issue V(t) loads; consumed after softmax
      uint4 vq[8];
#pragma unroll
      for (int c = 0; c < 8; ++c)
        vq[c] = *(const uint4*)(vb + c * 512);
      vb += 4096;

      // ---- QK^T: sacc[kh] = S[32*kh + key'][q] ----
      f32x16 sacc[2];
#pragma unroll
      for (int kh = 0; kh < 2; ++kh)
#pragma unroll
        for (int r = 0; r < 16; ++r) sacc[kh][r] = 0.f;
      __builtin_amdgcn_s_setprio(1);
#pragma unroll
      for (int ks = 0; ks < 4; ++ks)
#pragma unroll
        for (int kh = 0; kh < 2; ++kh) {
          union { short8_t v; uint4 u; } ku;
          ku.u = kq[ks * 2 + kh];
          sacc[kh] = __builtin_amdgcn_mfma_f32_32x32x16_bf16(ku.v, qf[ks], sacc[kh], 0, 0, 0);
        }
      __builtin_amdgcn_s_setprio(0);

      // prefetch K(t+1)
      if (t + 1 < t1) {
#pragma unroll
        for (int ks = 0; ks < 4; ++ks)
#pragma unroll
          for (int kh = 0; kh < 2; ++kh)
            kq[ks * 2 + kh] = *(const uint4*)(kb + (kh * 4 + ks) * 512);
        kb += 4096;
      }

      // ---- causal mask only on the diagonal (last) tile ----
      if (causal && t == nt - 1) {
        const int k0 = t * 64;
#pragma unroll
        for (int kh = 0; kh < 2; ++kh)
#pragma unroll
          for (int r = 0; r < 16; ++r)
            if (k0 + 32 * kh + (r & 3) + 8 * (r >> 2) + 4 * hi > qa) sacc[kh][r] = -3e38f;
      }

      // ---- row max: 4-partial tree ----
      float v0 = -3e38f, v1 = -3e38f, v2 = -3e38f, v3 = -3e38f;
#pragma unroll
      for (int kh = 0; kh < 2; ++kh)
#pragma unroll
        for (int r = 0; r < 16; r += 4) {
          v0 = fmaxf(v0, sacc[kh][r + 0]);
          v1 = fmaxf(v1, sacc[kh][r + 1]);
          v2 = fmaxf(v2, sacc[kh][r + 2]);
          v3 = fmaxf(v3, sacc[kh][r + 3]);
        }
      float vmax = fmaxf(fmaxf(v0, v1), fmaxf(v2, v3));
      vmax = fmaxf(vmax, __shfl_xor(vmax, 32));

      // defer-rescale (T13)
      if (__any(vmax > m_run + 44.3614196f)) {   // 8 / C2
        float mn = fmaxf(m_run, vmax);
        float alpha = exp2f((m_run - mn) * C2);
        den *= alpha;
#pragma unroll
        for (int d = 0; d < 2; ++d)
#pragma unroll
          for (int r = 0; r < 16; ++r) oacc[d][r] *= alpha;
        m_run = mn;
      }
      float mc2 = m_run * C2;
      float p0 = 0.f, p1 = 0.f, p2 = 0.f, p3 = 0.f;
#pragma unroll
      for (int kh = 0; kh < 2; ++kh)
#pragma unroll
        for (int r = 0; r < 16; r += 4) {
          float e0 = exp2f(fmaf(sacc[kh][r + 0], C2, -mc2));
          float e1 = exp2f(fmaf(sacc[kh][r + 1], C2, -mc2));
          float e2 = exp2f(fmaf(sacc[kh][r + 2], C2, -mc2));
          float e3 = exp2f(fmaf(sacc[kh][r + 3], C2, -mc2));
          sacc[kh][r + 0] = e0; sacc[kh][r + 1] = e1;
          sacc[kh][r + 2] = e2; sacc[kh][r + 3] = e3;
          p0 += e0; p1 += e1; p2 += e2; p3 += e3;
        }
      float psum = (p0 + p1) + (p2 + p3);
      psum += __shfl_xor(psum, 32);
      den += psum;

      // ---- build PV B-frags: pa[ks][j] = P[16*ks + 8*hi + j][q] ----
      short8_t pa[4];
#pragma unroll
      for (int ks = 0; ks < 4; ++ks) {
        const int blk = ks >> 1, kp = (ks & 1) * 8;
        uint wL0, wL1, wH0, wH1;
        asm("v_cvt_pk_bf16_f32 %0, %1, %2" : "=v"(wL0) : "v"(sacc[blk][kp + 0]), "v"(sacc[blk][kp + 1]));
        asm("v_cvt_pk_bf16_f32 %0, %1, %2" : "=v"(wL1) : "v"(sacc[blk][kp + 2]), "v"(sacc[blk][kp + 3]));
        asm("v_cvt_pk_bf16_f32 %0, %1, %2" : "=v"(wH0) : "v"(sacc[blk][kp + 4]), "v"(sacc[blk][kp + 5]));
        asm("v_cvt_pk_bf16_f32 %0, %1, %2" : "=v"(wH1) : "v"(sacc[blk][kp + 6]), "v"(sacc[blk][kp + 7]));
        uint s0 = hi ? wL0 : wH0, s1 = hi ? wL1 : wH1;
        uint r0 = __shfl_xor(s0, 32), r1 = __shfl_xor(s1, 32);
        union { short8_t v; uint u[4]; } pu;
        pu.u[0] = hi ? r0 : wL0;
        pu.u[1] = hi ? r1 : wL1;
        pu.u[2] = hi ? wH0 : r0;
        pu.u[3] = hi ? wH1 : r1;
        pa[ks] = pu.v;
      }

      // ---- PV: oacc[dh] = O^T[32*dh + d'][q] ----
      __builtin_amdgcn_s_setprio(1);
#pragma unroll
      for (int ks = 0; ks < 4; ++ks)
#pragma unroll
        for (int dh = 0; dh < 2; ++dh) {
          union { short8_t v; uint4 u; } vu;
          vu.u = vq[ks * 2 + dh];
          oacc[dh] = __builtin_amdgcn_mfma_f32_32x32x16_bf16(vu.v, pa[ks], oacc[dh], 0, 0, 0);
        }
      __builtin_amdgcn_s_setprio(0);
    }
  }

  // ---- deposit this wave's partial into LDS ----
#pragma unroll
  for (int dh = 0; dh < 2; ++dh)
#pragma unroll
    for (int rq = 0; rq < 4; ++rq) {
      uint a0, a1;
      asm("v_cvt_pk_bf16_f32 %0, %1, %2" : "=v"(a0) : "v"(oacc[dh][4 * rq + 0]), "v"(oacc[dh][4 * rq + 1]));
      asm("v_cvt_pk_bf16_f32 %0, %1, %2" : "=v"(a1) : "v"(oacc[dh][4 * rq + 2]), "v"(oacc[dh][4 * rq + 3]));
      uint2 dd; dd.x = a0; dd.y = a1;
      *(uint2*)&obf[w][q][32 * dh + 8 * rq + 4 * hi] = dd;
    }
  if (hi == 0) mdl[w][q] = make_float2(m_run, den);
  __syncthreads();

  // ---- 4-way merge: thread (qq = tid>>3, d8 = tid&7) handles 8 d-elements ----
  {
    const int qq = tid >> 3, d8 = tid & 7;
    float2 md0 = mdl[0][qq], md1 = mdl[1][qq], md2 = mdl[2][qq], md3 = mdl[3][qq];
    float mt = fmaxf(fmaxf(md0.x, md1.x), fmaxf(md2.x, md3.x));
    float w0 = exp2f((md0.x - mt) * C2);
    float w1 = exp2f((md1.x - mt) * C2);
    float w2 = exp2f((md2.x - mt) * C2);
    float w3 = exp2f((md3.x - mt) * C2);
    float inv = 1.f / (md0.y * w0 + md1.y * w1 + md2.y * w2 + md3.y * w3);

    uint4 a = *(const uint4*)&obf[0][qq][d8 * 8];
    uint4 b = *(const uint4*)&obf[1][qq][d8 * 8];
    uint4 c = *(const uint4*)&obf[2][qq][d8 * 8];
    uint4 d = *(const uint4*)&obf[3][qq][d8 * 8];
    const ushort* ap = (const ushort*)&a;
    const ushort* bp = (const ushort*)&b;
    const ushort* cp = (const ushort*)&c;
    const ushort* dp = (const ushort*)&d;
    ushort out8[8];
#pragma unroll
    for (int e = 0; e < 8; ++e) {
      float acc = bf2f(ap[e]) * w0 + bf2f(bp[e]) * w1 + bf2f(cp[e]) * w2 + bf2f(dp[e]) * w3;
      out8[e] = f2bf(acc * inv);
    }
    *(uint4*)(O + (size_t)(q0 + qq) * DMODEL + h * HDIM + d8 * 8) = *(const uint4*)out8;
  }
}

// ---------------- launch ----------------
extern "C" void kernel_launch(void* const* d_in, const int* in_sizes, int n_in,
                              void* d_out, int out_size, void* d_ws, size_t ws_size,
                              hipStream_t stream) {
  const float* x     = (const float*)d_in[0];
  const float* w_in  = (const float*)d_in[1];
  const float* w_out = (const float*)d_in[2];
  const int* icausal = (const int*)d_in[3];

  char* ws = (char*)d_ws;
  ushort* xbf    = (ushort*)(ws);                  // 4MB (vfrag reuses)
  ushort* winbf  = (ushort*)(ws + 4194304);        // 6MB (kfrag reuses after gemm1)
  ushort* woutbf = (ushort*)(ws + 10485760);       // 2MB
  ushort* qkv    = (ushort*)(ws + 12582912);       // 12MB
  ushort* obuf   = (ushort*)(ws + 25165824);       // 4MB
  ushort* vfrag  = xbf;                            // 16*32*4096*2B = 4MB
  ushort* kfrag  = winbf;                          // 4MB

  cvt_all<<<6144, 256, 0, stream>>>(x, w_in, w_out, xbf, winbf, woutbf);

  gemm_abt<128, 64, 1><<<16 * 48, 256, 0, stream>>>(xbf, winbf, (void*)qkv, 2048, 3072, 1024);
  transform_kv<<<512, 256, 0, stream>>>(qkv, kfrag, vfrag);
  attn_mfma<<<1024, 256, 0, stream>>>(qkv, kfrag, vfrag, obuf, icausal);
  gemm_abt<64, 64, 0><<<32 * 16, 256, 0, stream>>>(obuf, woutbf, d_out, 2048, 1024, 1024);
}

// Round 13
// 85.939 us; speedup vs baseline: 1.2442x; 1.0426x over previous
//
#include <hip/hip_runtime.h>
#include <stdint.h>

#define S_LEN 2048
#define DMODEL 1024
#define NHEAD 16
#define HDIM 64
#define NE 3072
#define C2 0.18033688011112042f  // 0.125 * log2(e)
#define RINV (-13.287712379549449f / 32.f)  // -log2(10000)/32

typedef __attribute__((ext_vector_type(8))) short short8_t;
typedef __attribute__((ext_vector_type(4))) float f32x4;
typedef __attribute__((ext_vector_type(16))) float f32x16;

__device__ __forceinline__ float bf2f(ushort u) {
  union { float f; uint32_t i; } c; c.i = ((uint32_t)u) << 16; return c.f;
}
__device__ __forceinline__ ushort f2bf(float f) {
  union { float f; uint32_t i; } c; c.f = f;
  uint32_t x = c.i;
  return (ushort)((x + 0x7fffu + ((x >> 16) & 1u)) >> 16);
}

__device__ __forceinline__ void gload_lds16(const ushort* g, ushort* l) {
  __builtin_amdgcn_global_load_lds(
      (const __attribute__((address_space(1))) void*)g,
      (__attribute__((address_space(3))) void*)l, 16, 0, 0);
}

// ---------------- fused fp32 -> bf16 convert (x, w_in, w_out) ----------------
__global__ void cvt_all(const float* __restrict__ x, const float* __restrict__ w_in,
                        const float* __restrict__ w_out,
                        ushort* __restrict__ xbf, ushort* __restrict__ winbf,
                        ushort* __restrict__ woutbf) {
  int i = blockIdx.x * blockDim.x + threadIdx.x;
  const float* src; ushort* dst; int off;
  if (i < 524288)       { src = x;     dst = xbf;    off = i; }
  else if (i < 1310720) { src = w_in;  dst = winbf;  off = i - 524288; }
  else                  { src = w_out; dst = woutbf; off = i - 1310720; }
  float4 v = ((const float4*)src)[off];
  ushort4 o;
  o.x = f2bf(v.x); o.y = f2bf(v.y); o.z = f2bf(v.z); o.w = f2bf(v.w);
  ((ushort4*)dst)[off] = o;
}

// ---------------- bf16 GEMM: C[M][N] = A[M][K] * B[N][K]^T, BK=64 ----------------
// Staging: wave chunk = 8 rows x 64 k (lane -> row l>>3, col (l&7)*8), chunk ch=w+4i,
// LDS linear [row][64]. 16 MFMA/wave between barrier pairs (m97 ratio) for 128x64.
template<int BM, int BN, int OUT_BF16>
__global__ __launch_bounds__(256) void gemm_abt(
    const ushort* __restrict__ A, const ushort* __restrict__ B,
    void* __restrict__ Cv, int M, int N, int K)
{
  constexpr int AR = BM / 32;
  constexpr int AC = BN / 32;
  constexpr int PG = (BM + BN) / 32;   // chunks of 8 rows, per wave
  __shared__ ushort lds[(BM + BN) * 64];

  const int nbn = N / BN;
  const int cpx = gridDim.x >> 3;
  const int bid = blockIdx.x;
  const int swz = (bid & 7) * cpx + (bid >> 3);
  const int bm = swz / nbn;
  const int bn = swz - bm * nbn;
  const int tid = threadIdx.x;
  const int w = tid >> 6, l = tid & 63;
  const int wm = w >> 1, wn = w & 1;
  const int fr = l & 15, fg = l >> 4;

  f32x4 acc[AR][AC];
#pragma unroll
  for (int r = 0; r < AR; ++r)
#pragma unroll
    for (int c = 0; c < AC; ++c) acc[r][c] = (f32x4){0.f, 0.f, 0.f, 0.f};

  const ushort* gsrc[PG];
  ushort* ldst[PG];
#pragma unroll
  for (int i = 0; i < PG; ++i) {
    int ch = w + 4 * i;
    int row = ch * 8 + (l >> 3);
    if (row < BM)
      gsrc[i] = A + (size_t)(bm * BM + row) * K + (l & 7) * 8;
    else
      gsrc[i] = B + (size_t)(bn * BN + (row - BM)) * K + (l & 7) * 8;
    ldst[i] = &lds[ch * 512];
  }

  const ushort* fa = &lds[(wm * (BM / 2) + fr) * 64 + fg * 8];
  const ushort* fb = &lds[BM * 64 + (wn * (BN / 2) + fr) * 64 + fg * 8];

  for (int k0 = 0; k0 < K; k0 += 64) {
    __syncthreads();
#pragma unroll
    for (int i = 0; i < PG; ++i) gload_lds16(gsrc[i] + k0, ldst[i]);
    __syncthreads();

    short8_t af[AR][2], bfr[AC][2];
#pragma unroll
    for (int r = 0; r < AR; ++r)
#pragma unroll
      for (int kk = 0; kk < 2; ++kk) {
        union { short8_t v; uint4 q; } u;
        u.q = *(const uint4*)(fa + r * 1024 + kk * 32);
        af[r][kk] = u.v;
      }
#pragma unroll
    for (int c = 0; c < AC; ++c)
#pragma unroll
      for (int kk = 0; kk < 2; ++kk) {
        union { short8_t v; uint4 q; } u;
        u.q = *(const uint4*)(fb + c * 1024 + kk * 32);
        bfr[c][kk] = u.v;
      }
    __builtin_amdgcn_s_setprio(1);
#pragma unroll
    for (int kk = 0; kk < 2; ++kk)
#pragma unroll
      for (int r = 0; r < AR; ++r)
#pragma unroll
        for (int c = 0; c < AC; ++c)
          acc[r][c] = __builtin_amdgcn_mfma_f32_16x16x32_bf16(af[r][kk], bfr[c][kk], acc[r][c], 0, 0, 0);
    __builtin_amdgcn_s_setprio(0);
  }

  const int row0 = bm * BM + wm * (BM / 2) + fg * 4;
  const int col0 = bn * BN + wn * (BN / 2) + fr;
#pragma unroll
  for (int r = 0; r < AR; ++r)
#pragma unroll
    for (int c = 0; c < AC; ++c)
#pragma unroll
      for (int j = 0; j < 4; ++j) {
        int row = row0 + r * 16 + j;
        int col = col0 + c * 16;
        if (OUT_BF16)
          ((ushort*)Cv)[(size_t)row * N + col] = f2bf(acc[r][c][j]);
        else
          ((float*)Cv)[(size_t)row * N + col] = acc[r][c][j];
      }
}

// ---------------- K/V -> fragment-major buffers, K-RoPE fused in LDS ----------------
__global__ __launch_bounds__(256) void transform_kv(
    const ushort* __restrict__ qkv, ushort* __restrict__ kfrag, ushort* __restrict__ vfrag)
{
  __shared__ ushort Kt[64][72];
  __shared__ ushort Vt[64][72];
  const int h = blockIdx.x & 15, t = blockIdx.x >> 4;
  const int tid = threadIdx.x;
#pragma unroll
  for (int it = 0; it < 2; ++it) {
    int idx = tid + 256 * it;
    int key = idx >> 3, d8 = (idx & 7) << 3;
    const ushort* src = qkv + (size_t)(t * 64 + key) * NE + DMODEL + h * HDIM + d8;
    *(uint4*)&Kt[key][d8] = *(const uint4*)src;
    *(uint4*)&Vt[key][d8] = *(const uint4*)(src + DMODEL);
  }
  __syncthreads();

  // --- RoPE on K in LDS: pair (i, i+32) per key; 8 keys per thread ---
  {
    const int i = tid & 31;
    const int k8 = (tid >> 5) * 8;
    float invf = exp2f((float)i * RINV);
#pragma unroll
    for (int kk = 0; kk < 8; ++kk) {
      int key = k8 + kk;
      float sn, cs;
      sincosf((float)(t * 64 + key) * invf, &sn, &cs);
      float x1 = bf2f(Kt[key][i]), x2 = bf2f(Kt[key][i + 32]);
      Kt[key][i]      = f2bf(x1 * cs - x2 * sn);
      Kt[key][i + 32] = f2bf(x2 * cs + x1 * sn);
    }
  }
  __syncthreads();

  ushort* kb = kfrag + (size_t)(h * 32 + t) * 4096;
  ushort* vb = vfrag + (size_t)(h * 32 + t) * 4096;
#pragma unroll
  for (int it = 0; it < 2; ++it) {
    int idx = tid + 256 * it;       // 0..511
    int c = idx >> 6, l = idx & 63;
    int q = l & 31, hi = l >> 5;
    int kh = c >> 2, ks = c & 3;
    uint4 v = *(const uint4*)&Kt[32 * kh + q][16 * ks + 8 * hi];
    *(uint4*)(kb + idx * 8) = v;
  }
#pragma unroll
  for (int it = 0; it < 2; ++it) {
    int idx = tid + 256 * it;
    int c = idx >> 6, l = idx & 63;
    int q = l & 31, hi = l >> 5;
    int ks = c >> 1, dh = c & 1;
    ushort tmp[8];
#pragma unroll
    for (int jj = 0; jj < 8; ++jj)
      tmp[jj] = Vt[16 * ks + 8 * hi + jj][32 * dh + q];
    *(uint4*)(vb + idx * 8) = *(const uint4*)tmp;
  }
}

// ---------------- MFMA flash attention: in-block split-K, Q-RoPE in-register ----------------
__global__ __launch_bounds__(256) void attn_mfma(
    const ushort* __restrict__ qkv, const ushort* __restrict__ kfrag,
    const ushort* __restrict__ vfrag, ushort* __restrict__ O,
    const int* __restrict__ icausal)
{
  __shared__ ushort obf[4][32][68];   // per-wave unnormalized O^T, bf16, pad-68
  __shared__ float2 mdl[4][32];       // per-wave {m, den}

  const int h = blockIdx.x & 15;
  const int i = blockIdx.x >> 4;      // 0..63
  const int g = i & 15, k = i >> 4;   // k = grid quarter (CU stride class)
  const int qt = (k == 0) ? g : (k == 1) ? (63 - g) : (k == 2) ? (31 - g) : (32 + g);

  const int causal = *icausal;
  const int nt = causal ? ((qt >> 1) + 1) : (S_LEN / 64);

  const int tid = threadIdx.x;
  const int w = tid >> 6, l = tid & 63;
  const int q = l & 31, hi = l >> 5;
  const int q0 = qt * 32;
  const int qa = q0 + q;
  const int t0 = w * nt / 4, t1 = (w + 1) * nt / 4;

  // Q B-fragments + in-register RoPE: pairs (qf[0],qf[2]) and (qf[1],qf[3])
  short8_t qf[4];
  {
    const ushort* qp = qkv + (size_t)qa * NE + h * HDIM + 8 * hi;
#pragma unroll
    for (int ks = 0; ks < 4; ++ks) {
      union { short8_t v; uint4 u; } uu;
      uu.u = *(const uint4*)(qp + 16 * ks);
      qf[ks] = uu.v;
    }
    union { short8_t v; ushort u[8]; } a0, a1, b0, b1;
    a0.v = qf[0]; a1.v = qf[1]; b0.v = qf[2]; b1.v = qf[3];
#pragma unroll
    for (int j = 0; j < 8; ++j) {
      {
        float invf = exp2f((float)(8 * hi + j) * RINV);
        float sn, cs; sincosf((float)qa * invf, &sn, &cs);
        float x1 = bf2f(a0.u[j]), x2 = bf2f(b0.u[j]);
        a0.u[j] = f2bf(x1 * cs - x2 * sn);
        b0.u[j] = f2bf(x2 * cs + x1 * sn);
      }
      {
        float invf = exp2f((float)(16 + 8 * hi + j) * RINV);
        float sn, cs; sincosf((float)qa * invf, &sn, &cs);
        float x1 = bf2f(a1.u[j]), x2 = bf2f(b1.u[j]);
        a1.u[j] = f2bf(x1 * cs - x2 * sn);
        b1.u[j] = f2bf(x2 * cs + x1 * sn);
      }
    }
    qf[0] = a0.v; qf[1] = a1.v; qf[2] = b0.v; qf[3] = b1.v;
  }

  const ushort* kb = kfrag + (size_t)(h * 32 + t0) * 4096 + l * 8;
  const ushort* vb = vfrag + (size_t)(h * 32 + t0) * 4096 + l * 8;

  float m_run = -1e30f, den = 0.f;
  f32x16 oacc[2];
#pragma unroll
  for (int d = 0; d < 2; ++d)
#pragma unroll
    for (int r = 0; r < 16; ++r) oacc[d][r] = 0.f;

  if (t0 < t1) {
    uint4 kq[8];
#pragma unroll
    for (int ks = 0; ks < 4; ++ks)
#pragma unroll
      for (int kh = 0; kh < 2; ++kh)
        kq[ks * 2 + kh] = *(const uint4*)(kb + (kh * 4 + ks) * 512);
    kb += 4096;

    for (int t = t0; t < t1; ++t) {
      uint4 vq[8];
#pragma unroll
      for (int c = 0; c < 8; ++c)
        vq[c] = *(const uint4*)(vb + c * 512);
      vb += 4096;

      f32x16 sacc[2];
#pragma unroll
      for (int kh = 0; kh < 2; ++kh)
#pragma unroll
        for (int r = 0; r < 16; ++r) sacc[kh][r] = 0.f;
      __builtin_amdgcn_s_setprio(1);
#pragma unroll
      for (int ks = 0; ks < 4; ++ks)
#pragma unroll
        for (int kh = 0; kh < 2; ++kh) {
          union { short8_t v; uint4 u; } ku;
          ku.u = kq[ks * 2 + kh];
          sacc[kh] = __builtin_amdgcn_mfma_f32_32x32x16_bf16(ku.v, qf[ks], sacc[kh], 0, 0, 0);
        }
      __builtin_amdgcn_s_setprio(0);

      if (t + 1 < t1) {
#pragma unroll
        for (int ks = 0; ks < 4; ++ks)
#pragma unroll
          for (int kh = 0; kh < 2; ++kh)
            kq[ks * 2 + kh] = *(const uint4*)(kb + (kh * 4 + ks) * 512);
        kb += 4096;
      }

      if (causal && t == nt - 1) {
        const int k0 = t * 64;
#pragma unroll
        for (int kh = 0; kh < 2; ++kh)
#pragma unroll
          for (int r = 0; r < 16; ++r)
            if (k0 + 32 * kh + (r & 3) + 8 * (r >> 2) + 4 * hi > qa) sacc[kh][r] = -3e38f;
      }

      float v0 = -3e38f, v1 = -3e38f, v2 = -3e38f, v3 = -3e38f;
#pragma unroll
      for (int kh = 0; kh < 2; ++kh)
#pragma unroll
        for (int r = 0; r < 16; r += 4) {
          v0 = fmaxf(v0, sacc[kh][r + 0]);
          v1 = fmaxf(v1, sacc[kh][r + 1]);
          v2 = fmaxf(v2, sacc[kh][r + 2]);
          v3 = fmaxf(v3, sacc[kh][r + 3]);
        }
      float vmax = fmaxf(fmaxf(v0, v1), fmaxf(v2, v3));
      vmax = fmaxf(vmax, __shfl_xor(vmax, 32));

      if (__any(vmax > m_run + 44.3614196f)) {   // 8 / C2
        float mn = fmaxf(m_run, vmax);
        float alpha = exp2f((m_run - mn) * C2);
        den *= alpha;
#pragma unroll
        for (int d = 0; d < 2; ++d)
#pragma unroll
          for (int r = 0; r < 16; ++r) oacc[d][r] *= alpha;
        m_run = mn;
      }
      float mc2 = m_run * C2;
      float p0 = 0.f, p1 = 0.f, p2 = 0.f, p3 = 0.f;
#pragma unroll
      for (int kh = 0; kh < 2; ++kh)
#pragma unroll
        for (int r = 0; r < 16; r += 4) {
          float e0 = exp2f(fmaf(sacc[kh][r + 0], C2, -mc2));
          float e1 = exp2f(fmaf(sacc[kh][r + 1], C2, -mc2));
          float e2 = exp2f(fmaf(sacc[kh][r + 2], C2, -mc2));
          float e3 = exp2f(fmaf(sacc[kh][r + 3], C2, -mc2));
          sacc[kh][r + 0] = e0; sacc[kh][r + 1] = e1;
          sacc[kh][r + 2] = e2; sacc[kh][r + 3] = e3;
          p0 += e0; p1 += e1; p2 += e2; p3 += e3;
        }
      float psum = (p0 + p1) + (p2 + p3);
      psum += __shfl_xor(psum, 32);
      den += psum;

      short8_t pa[4];
#pragma unroll
      for (int ks = 0; ks < 4; ++ks) {
        const int blk = ks >> 1, kp = (ks & 1) * 8;
        uint wL0, wL1, wH0, wH1;
        asm("v_cvt_pk_bf16_f32 %0, %1, %2" : "=v"(wL0) : "v"(sacc[blk][kp + 0]), "v"(sacc[blk][kp + 1]));
        asm("v_cvt_pk_bf16_f32 %0, %1, %2" : "=v"(wL1) : "v"(sacc[blk][kp + 2]), "v"(sacc[blk][kp + 3]));
        asm("v_cvt_pk_bf16_f32 %0, %1, %2" : "=v"(wH0) : "v"(sacc[blk][kp + 4]), "v"(sacc[blk][kp + 5]));
        asm("v_cvt_pk_bf16_f32 %0, %1, %2" : "=v"(wH1) : "v"(sacc[blk][kp + 6]), "v"(sacc[blk][kp + 7]));
        uint s0 = hi ? wL0 : wH0, s1 = hi ? wL1 : wH1;
        uint r0 = __shfl_xor(s0, 32), r1 = __shfl_xor(s1, 32);
        union { short8_t v; uint u[4]; } pu;
        pu.u[0] = hi ? r0 : wL0;
        pu.u[1] = hi ? r1 : wL1;
        pu.u[2] = hi ? wH0 : r0;
        pu.u[3] = hi ? wH1 : r1;
        pa[ks] = pu.v;
      }

      __builtin_amdgcn_s_setprio(1);
#pragma unroll
      for (int ks = 0; ks < 4; ++ks)
#pragma unroll
        for (int dh = 0; dh < 2; ++dh) {
          union { short8_t v; uint4 u; } vu;
          vu.u = vq[ks * 2 + dh];
          oacc[dh] = __builtin_amdgcn_mfma_f32_32x32x16_bf16(vu.v, pa[ks], oacc[dh], 0, 0, 0);
        }
      __builtin_amdgcn_s_setprio(0);
    }
  }

#pragma unroll
  for (int dh = 0; dh < 2; ++dh)
#pragma unroll
    for (int rq = 0; rq < 4; ++rq) {
      uint a0, a1;
      asm("v_cvt_pk_bf16_f32 %0, %1, %2" : "=v"(a0) : "v"(oacc[dh][4 * rq + 0]), "v"(oacc[dh][4 * rq + 1]));
      asm("v_cvt_pk_bf16_f32 %0, %1, %2" : "=v"(a1) : "v"(oacc[dh][4 * rq + 2]), "v"(oacc[dh][4 * rq + 3]));
      uint2 dd; dd.x = a0; dd.y = a1;
      *(uint2*)&obf[w][q][32 * dh + 8 * rq + 4 * hi] = dd;
    }
  if (hi == 0) mdl[w][q] = make_float2(m_run, den);
  __syncthreads();

  {
    const int qq = tid >> 3, d8 = tid & 7;
    float2 md0 = mdl[0][qq], md1 = mdl[1][qq], md2 = mdl[2][qq], md3 = mdl[3][qq];
    float mt = fmaxf(fmaxf(md0.x, md1.x), fmaxf(md2.x, md3.x));
    float w0 = exp2f((md0.x - mt) * C2);
    float w1 = exp2f((md1.x - mt) * C2);
    float w2 = exp2f((md2.x - mt) * C2);
    float w3 = exp2f((md3.x - mt) * C2);
    float inv = 1.f / (md0.y * w0 + md1.y * w1 + md2.y * w2 + md3.y * w3);

    uint4 a = *(const uint4*)&obf[0][qq][d8 * 8];
    uint4 b = *(const uint4*)&obf[1][qq][d8 * 8];
    uint4 c = *(const uint4*)&obf[2][qq][d8 * 8];
    uint4 d = *(const uint4*)&obf[3][qq][d8 * 8];
    const ushort* ap = (const ushort*)&a;
    const ushort* bp = (const ushort*)&b;
    const ushort* cp = (const ushort*)&c;
    const ushort* dp = (const ushort*)&d;
    ushort out8[8];
#pragma unroll
    for (int e = 0; e < 8; ++e) {
      float acc = bf2f(ap[e]) * w0 + bf2f(bp[e]) * w1 + bf2f(cp[e]) * w2 + bf2f(dp[e]) * w3;
      out8[e] = f2bf(acc * inv);
    }
    *(uint4*)(O + (size_t)(q0 + qq) * DMODEL + h * HDIM + d8 * 8) = *(const uint4*)out8;
  }
}

// ---------------- launch ----------------
extern "C" void kernel_launch(void* const* d_in, const int* in_sizes, int n_in,
                              void* d_out, int out_size, void* d_ws, size_t ws_size,
                              hipStream_t stream) {
  const float* x     = (const float*)d_in[0];
  const float* w_in  = (const float*)d_in[1];
  const float* w_out = (const float*)d_in[2];
  const int* icausal = (const int*)d_in[3];

  char* ws = (char*)d_ws;
  ushort* xbf    = (ushort*)(ws);                  // 4MB (vfrag reuses)
  ushort* winbf  = (ushort*)(ws + 4194304);        // 6MB (kfrag reuses after gemm1)
  ushort* woutbf = (ushort*)(ws + 10485760);       // 2MB
  ushort* qkv    = (ushort*)(ws + 12582912);       // 12MB
  ushort* obuf   = (ushort*)(ws + 25165824);       // 4MB
  ushort* vfrag  = xbf;                            // 16*32*4096*2B = 4MB
  ushort* kfrag  = winbf;                          // 4MB

  cvt_all<<<6144, 256, 0, stream>>>(x, w_in, w_out, xbf, winbf, woutbf);

  gemm_abt<128, 64, 1><<<16 * 48, 256, 0, stream>>>(xbf, winbf, (void*)qkv, 2048, 3072, 1024);
  transform_kv<<<512, 256, 0, stream>>>(qkv, kfrag, vfrag);
  attn_mfma<<<1024, 256, 0, stream>>>(qkv, kfrag, vfrag, obuf, icausal);
  gemm_abt<64, 64, 0><<<32 * 16, 256, 0, stream>>>(obuf, woutbf, d_out, 2048, 1024, 1024);
}

// Round 15
// 81.229 us; speedup vs baseline: 1.3163x; 1.0580x over previous
//
#include <hip/hip_runtime.h>
#include <stdint.h>

#define S_LEN 2048
#define DMODEL 1024
#define NHEAD 16
#define HDIM 64
#define NE 3072
#define C2 0.18033688011112042f  // 0.125 * log2(e)
#define RINV (-13.287712379549449f / 32.f)  // -log2(10000)/32

typedef __attribute__((ext_vector_type(8))) short short8_t;
typedef __attribute__((ext_vector_type(4))) float f32x4;
typedef __attribute__((ext_vector_type(16))) float f32x16;

__device__ __forceinline__ float bf2f(ushort u) {
  union { float f; uint32_t i; } c; c.i = ((uint32_t)u) << 16; return c.f;
}
__device__ __forceinline__ ushort f2bf(float f) {
  union { float f; uint32_t i; } c; c.f = f;
  uint32_t x = c.i;
  return (ushort)((x + 0x7fffu + ((x >> 16) & 1u)) >> 16);
}

__device__ __forceinline__ void gload_lds16(const ushort* g, ushort* l) {
  __builtin_amdgcn_global_load_lds(
      (const __attribute__((address_space(1))) void*)g,
      (__attribute__((address_space(3))) void*)l, 16, 0, 0);
}

// ---------------- fused fp32 -> bf16 convert (x, w_in, w_out) ----------------
__global__ void cvt_all(const float* __restrict__ x, const float* __restrict__ w_in,
                        const float* __restrict__ w_out,
                        ushort* __restrict__ xbf, ushort* __restrict__ winbf,
                        ushort* __restrict__ woutbf) {
  int i = blockIdx.x * blockDim.x + threadIdx.x;
  const float* src; ushort* dst; int off;
  if (i < 524288)       { src = x;     dst = xbf;    off = i; }
  else if (i < 1310720) { src = w_in;  dst = winbf;  off = i - 524288; }
  else                  { src = w_out; dst = woutbf; off = i - 1310720; }
  float4 v = ((const float4*)src)[off];
  ushort4 o;
  o.x = f2bf(v.x); o.y = f2bf(v.y); o.z = f2bf(v.z); o.w = f2bf(v.w);
  ((ushort4*)dst)[off] = o;
}

// ---------------- bf16 GEMM: C[M][N] = A[M][K] * B[N][K]^T, BK=64 ----------------
// MODE 0: fp32 output to Cv[M][N] (gemm2).
// MODE 2: fused qkv epilogue (gemm1, BM=128/BN=64): bn<16 -> Q to qbuf (stride 1024);
//         bn 16..31 -> K: LDS bounce + RoPE + fragment-pack to kfrag;
//         bn 32..47 -> V: LDS bounce + transpose-pack to vfrag.
template<int BM, int BN, int MODE>
__global__ __launch_bounds__(256) void gemm_abt(
    const ushort* __restrict__ A, const ushort* __restrict__ B,
    void* __restrict__ Cv, ushort* __restrict__ kfrag, ushort* __restrict__ vfrag,
    int M, int N, int K)
{
  constexpr int AR = BM / 32;
  constexpr int AC = BN / 32;
  constexpr int PG = (BM + BN) / 32;   // chunks of 8 rows, per wave
  __shared__ ushort lds[(BM + BN) * 64];

  const int nbn = N / BN;
  const int cpx = gridDim.x >> 3;
  const int bid = blockIdx.x;
  const int swz = (bid & 7) * cpx + (bid >> 3);
  const int bm = swz / nbn;
  const int bn = swz - bm * nbn;
  const int tid = threadIdx.x;
  const int w = tid >> 6, l = tid & 63;
  const int wm = w >> 1, wn = w & 1;
  const int fr = l & 15, fg = l >> 4;

  f32x4 acc[AR][AC];
#pragma unroll
  for (int r = 0; r < AR; ++r)
#pragma unroll
    for (int c = 0; c < AC; ++c) acc[r][c] = (f32x4){0.f, 0.f, 0.f, 0.f};

  const ushort* gsrc[PG];
  ushort* ldst[PG];
#pragma unroll
  for (int i = 0; i < PG; ++i) {
    int ch = w + 4 * i;
    int row = ch * 8 + (l >> 3);
    if (row < BM)
      gsrc[i] = A + (size_t)(bm * BM + row) * K + (l & 7) * 8;
    else
      gsrc[i] = B + (size_t)(bn * BN + (row - BM)) * K + (l & 7) * 8;
    ldst[i] = &lds[ch * 512];
  }

  const ushort* fa = &lds[(wm * (BM / 2) + fr) * 64 + fg * 8];
  const ushort* fb = &lds[BM * 64 + (wn * (BN / 2) + fr) * 64 + fg * 8];

  for (int k0 = 0; k0 < K; k0 += 64) {
    __syncthreads();
#pragma unroll
    for (int i = 0; i < PG; ++i) gload_lds16(gsrc[i] + k0, ldst[i]);
    __syncthreads();

    short8_t af[AR][2], bfr[AC][2];
#pragma unroll
    for (int r = 0; r < AR; ++r)
#pragma unroll
      for (int kk = 0; kk < 2; ++kk) {
        union { short8_t v; uint4 q; } u;
        u.q = *(const uint4*)(fa + r * 1024 + kk * 32);
        af[r][kk] = u.v;
      }
#pragma unroll
    for (int c = 0; c < AC; ++c)
#pragma unroll
      for (int kk = 0; kk < 2; ++kk) {
        union { short8_t v; uint4 q; } u;
        u.q = *(const uint4*)(fb + c * 1024 + kk * 32);
        bfr[c][kk] = u.v;
      }
    __builtin_amdgcn_s_setprio(1);
#pragma unroll
    for (int kk = 0; kk < 2; ++kk)
#pragma unroll
      for (int r = 0; r < AR; ++r)
#pragma unroll
        for (int c = 0; c < AC; ++c)
          acc[r][c] = __builtin_amdgcn_mfma_f32_16x16x32_bf16(af[r][kk], bfr[c][kk], acc[r][c], 0, 0, 0);
    __builtin_amdgcn_s_setprio(0);
  }

  if constexpr (MODE == 0) {
    const int row0 = bm * BM + wm * (BM / 2) + fg * 4;
    const int col0 = bn * BN + wn * (BN / 2) + fr;
#pragma unroll
    for (int r = 0; r < AR; ++r)
#pragma unroll
      for (int c = 0; c < AC; ++c)
#pragma unroll
        for (int j = 0; j < 4; ++j)
          ((float*)Cv)[(size_t)(row0 + r * 16 + j) * N + col0 + c * 16] = acc[r][c][j];
  } else {
    const int cls = bn >> 4;        // 0=Q, 1=K, 2=V
    const int h = bn & 15;
    if (cls == 0) {
      // Q -> qbuf [M][1024], head h columns
      const int row0 = bm * BM + wm * (BM / 2) + fg * 4;
      const int colq = bn * 64 + wn * 32 + fr;   // bn<16: global q-col
      ushort* qb = (ushort*)Cv;
#pragma unroll
      for (int r = 0; r < AR; ++r)
#pragma unroll
        for (int c = 0; c < AC; ++c)
#pragma unroll
          for (int j = 0; j < 4; ++j)
            qb[(size_t)(row0 + r * 16 + j) * 1024 + colq + c * 16] = f2bf(acc[r][c][j]);
    } else {
      // bounce acc -> LDS tile T[128][72] (bf16), then pack fragments
      __syncthreads();                 // all waves done reading staging LDS
      ushort* T = lds;
#pragma unroll
      for (int r = 0; r < AR; ++r)
#pragma unroll
        for (int c = 0; c < AC; ++c)
#pragma unroll
          for (int j = 0; j < 4; ++j) {
            int rl = wm * 64 + r * 16 + fg * 4 + j;   // FIX: fg*4 was missing
            int cl = wn * 32 + c * 16 + fr;
            T[rl * 72 + cl] = f2bf(acc[r][c][j]);
          }
      __syncthreads();

      if (cls == 1) {
        // RoPE on K rows in LDS: pair (i, i+32); 128 keys, 16 per thread-group row
        const int ii = tid & 31;
        const float invf = exp2f((float)ii * RINV);
#pragma unroll
        for (int kk = 0; kk < 16; ++kk) {
          int key = (tid >> 5) * 16 + kk;
          float sn, cs;
          sincosf((float)(bm * 128 + key) * invf, &sn, &cs);
          float x1 = bf2f(T[key * 72 + ii]), x2 = bf2f(T[key * 72 + ii + 32]);
          T[key * 72 + ii]      = f2bf(x1 * cs - x2 * sn);
          T[key * 72 + ii + 32] = f2bf(x2 * cs + x1 * sn);
        }
        __syncthreads();
        // pack kfrag: tile t = bm*2+tt; chunk c=kh*4+ks, lane l: K[64tt+32kh+q][16ks+8hi..]
#pragma unroll
        for (int it = 0; it < 4; ++it) {
          int idx = tid + 256 * it;          // 0..1023
          int tt = idx >> 9, e = idx & 511;
          int c2 = e >> 6, l2 = e & 63, q2 = l2 & 31, hi2 = l2 >> 5;
          int kh = c2 >> 2, ks = c2 & 3;
          uint4 v = *(const uint4*)&T[(64 * tt + 32 * kh + q2) * 72 + 16 * ks + 8 * hi2];
          *(uint4*)(kfrag + (size_t)(h * 32 + bm * 2 + tt) * 4096 + e * 8) = v;
        }
      } else {
        // pack vfrag: chunk c=ks*2+dh, lane l: V[64tt+16ks+8hi+jj][32dh+q]
#pragma unroll
        for (int it = 0; it < 4; ++it) {
          int idx = tid + 256 * it;
          int tt = idx >> 9, e = idx & 511;
          int c2 = e >> 6, l2 = e & 63, q2 = l2 & 31, hi2 = l2 >> 5;
          int ks = c2 >> 1, dh = c2 & 1;
          ushort tmp[8];
#pragma unroll
          for (int jj = 0; jj < 8; ++jj)
            tmp[jj] = T[(64 * tt + 16 * ks + 8 * hi2 + jj) * 72 + 32 * dh + q2];
          *(uint4*)(vfrag + (size_t)(h * 32 + bm * 2 + tt) * 4096 + e * 8) = *(const uint4*)tmp;
        }
      }
    }
  }
}

// ---------------- MFMA flash attention: in-block split-K, Q-RoPE in-register ----------------
__global__ __launch_bounds__(256) void attn_mfma(
    const ushort* __restrict__ qbuf, const ushort* __restrict__ kfrag,
    const ushort* __restrict__ vfrag, ushort* __restrict__ O,
    const int* __restrict__ icausal)
{
  __shared__ ushort obf[4][32][68];   // per-wave unnormalized O^T, bf16, pad-68
  __shared__ float2 mdl[4][32];       // per-wave {m, den}

  const int h = blockIdx.x & 15;
  const int i = blockIdx.x >> 4;      // 0..63
  const int g = i & 15, k = i >> 4;   // k = grid quarter (CU stride class)
  const int qt = (k == 0) ? g : (k == 1) ? (63 - g) : (k == 2) ? (31 - g) : (32 + g);

  const int causal = *icausal;
  const int nt = causal ? ((qt >> 1) + 1) : (S_LEN / 64);

  const int tid = threadIdx.x;
  const int w = tid >> 6, l = tid & 63;
  const int q = l & 31, hi = l >> 5;
  const int q0 = qt * 32;
  const int qa = q0 + q;
  const int t0 = w * nt / 4, t1 = (w + 1) * nt / 4;

  // Q B-fragments + in-register RoPE: pairs (qf[0],qf[2]) and (qf[1],qf[3])
  short8_t qf[4];
  {
    const ushort* qp = qbuf + (size_t)qa * 1024 + h * HDIM + 8 * hi;
#pragma unroll
    for (int ks = 0; ks < 4; ++ks) {
      union { short8_t v; uint4 u; } uu;
      uu.u = *(const uint4*)(qp + 16 * ks);
      qf[ks] = uu.v;
    }
    union { short8_t v; ushort u[8]; } a0, a1, b0, b1;
    a0.v = qf[0]; a1.v = qf[1]; b0.v = qf[2]; b1.v = qf[3];
#pragma unroll
    for (int j = 0; j < 8; ++j) {
      {
        float invf = exp2f((float)(8 * hi + j) * RINV);
        float sn, cs; sincosf((float)qa * invf, &sn, &cs);
        float x1 = bf2f(a0.u[j]), x2 = bf2f(b0.u[j]);
        a0.u[j] = f2bf(x1 * cs - x2 * sn);
        b0.u[j] = f2bf(x2 * cs + x1 * sn);
      }
      {
        float invf = exp2f((float)(16 + 8 * hi + j) * RINV);
        float sn, cs; sincosf((float)qa * invf, &sn, &cs);
        float x1 = bf2f(a1.u[j]), x2 = bf2f(b1.u[j]);
        a1.u[j] = f2bf(x1 * cs - x2 * sn);
        b1.u[j] = f2bf(x2 * cs + x1 * sn);
      }
    }
    qf[0] = a0.v; qf[1] = a1.v; qf[2] = b0.v; qf[3] = b1.v;
  }

  const ushort* kb = kfrag + (size_t)(h * 32 + t0) * 4096 + l * 8;
  const ushort* vb = vfrag + (size_t)(h * 32 + t0) * 4096 + l * 8;

  float m_run = -1e30f, den = 0.f;
  f32x16 oacc[2];
#pragma unroll
  for (int d = 0; d < 2; ++d)
#pragma unroll
    for (int r = 0; r < 16; ++r) oacc[d][r] = 0.f;

  if (t0 < t1) {
    uint4 kq[8];
#pragma unroll
    for (int ks = 0; ks < 4; ++ks)
#pragma unroll
      for (int kh = 0; kh < 2; ++kh)
        kq[ks * 2 + kh] = *(const uint4*)(kb + (kh * 4 + ks) * 512);
    kb += 4096;

    for (int t = t0; t < t1; ++t) {
      uint4 vq[8];
#pragma unroll
      for (int c = 0; c < 8; ++c)
        vq[c] = *(const uint4*)(vb + c * 512);
      vb += 4096;

      f32x16 sacc[2];
#pragma unroll
      for (int kh = 0; kh < 2; ++kh)
#pragma unroll
        for (int r = 0; r < 16; ++r) sacc[kh][r] = 0.f;
      __builtin_amdgcn_s_setprio(1);
#pragma unroll
      for (int ks = 0; ks < 4; ++ks)
#pragma unroll
        for (int kh = 0; kh < 2; ++kh) {
          union { short8_t v; uint4 u; } ku;
          ku.u = kq[ks * 2 + kh];
          sacc[kh] = __builtin_amdgcn_mfma_f32_32x32x16_bf16(ku.v, qf[ks], sacc[kh], 0, 0, 0);
        }
      __builtin_amdgcn_s_setprio(0);

      if (t + 1 < t1) {
#pragma unroll
        for (int ks = 0; ks < 4; ++ks)
#pragma unroll
          for (int kh = 0; kh < 2; ++kh)
            kq[ks * 2 + kh] = *(const uint4*)(kb + (kh * 4 + ks) * 512);
        kb += 4096;
      }

      if (causal && t == nt - 1) {
        const int k0 = t * 64;
#pragma unroll
        for (int kh = 0; kh < 2; ++kh)
#pragma unroll
          for (int r = 0; r < 16; ++r)
            if (k0 + 32 * kh + (r & 3) + 8 * (r >> 2) + 4 * hi > qa) sacc[kh][r] = -3e38f;
      }

      float v0 = -3e38f, v1 = -3e38f, v2 = -3e38f, v3 = -3e38f;
#pragma unroll
      for (int kh = 0; kh < 2; ++kh)
#pragma unroll
        for (int r = 0; r < 16; r += 4) {
          v0 = fmaxf(v0, sacc[kh][r + 0]);
          v1 = fmaxf(v1, sacc[kh][r + 1]);
          v2 = fmaxf(v2, sacc[kh][r + 2]);
          v3 = fmaxf(v3, sacc[kh][r + 3]);
        }
      float vmax = fmaxf(fmaxf(v0, v1), fmaxf(v2, v3));
      vmax = fmaxf(vmax, __shfl_xor(vmax, 32));

      if (__any(vmax > m_run + 44.3614196f)) {   // 8 / C2
        float mn = fmaxf(m_run, vmax);
        float alpha = exp2f((m_run - mn) * C2);
        den *= alpha;
#pragma unroll
        for (int d = 0; d < 2; ++d)
#pragma unroll
          for (int r = 0; r < 16; ++r) oacc[d][r] *= alpha;
        m_run = mn;
      }
      float mc2 = m_run * C2;
      float p0 = 0.f, p1 = 0.f, p2 = 0.f, p3 = 0.f;
#pragma unroll
      for (int kh = 0; kh < 2; ++kh)
#pragma unroll
        for (int r = 0; r < 16; r += 4) {
          float e0 = exp2f(fmaf(sacc[kh][r + 0], C2, -mc2));
          float e1 = exp2f(fmaf(sacc[kh][r + 1], C2, -mc2));
          float e2 = exp2f(fmaf(sacc[kh][r + 2], C2, -mc2));
          float e3 = exp2f(fmaf(sacc[kh][r + 3], C2, -mc2));
          sacc[kh][r + 0] = e0; sacc[kh][r + 1] = e1;
          sacc[kh][r + 2] = e2; sacc[kh][r + 3] = e3;
          p0 += e0; p1 += e1; p2 += e2; p3 += e3;
        }
      float psum = (p0 + p1) + (p2 + p3);
      psum += __shfl_xor(psum, 32);
      den += psum;

      short8_t pa[4];
#pragma unroll
      for (int ks = 0; ks < 4; ++ks) {
        const int blk = ks >> 1, kp = (ks & 1) * 8;
        uint wL0, wL1, wH0, wH1;
        asm("v_cvt_pk_bf16_f32 %0, %1, %2" : "=v"(wL0) : "v"(sacc[blk][kp + 0]), "v"(sacc[blk][kp + 1]));
        asm("v_cvt_pk_bf16_f32 %0, %1, %2" : "=v"(wL1) : "v"(sacc[blk][kp + 2]), "v"(sacc[blk][kp + 3]));
        asm("v_cvt_pk_bf16_f32 %0, %1, %2" : "=v"(wH0) : "v"(sacc[blk][kp + 4]), "v"(sacc[blk][kp + 5]));
        asm("v_cvt_pk_bf16_f32 %0, %1, %2" : "=v"(wH1) : "v"(sacc[blk][kp + 6]), "v"(sacc[blk][kp + 7]));
        uint s0 = hi ? wL0 : wH0, s1 = hi ? wL1 : wH1;
        uint r0 = __shfl_xor(s0, 32), r1 = __shfl_xor(s1, 32);
        union { short8_t v; uint u[4]; } pu;
        pu.u[0] = hi ? r0 : wL0;
        pu.u[1] = hi ? r1 : wL1;
        pu.u[2] = hi ? wH0 : r0;
        pu.u[3] = hi ? wH1 : r1;
        pa[ks] = pu.v;
      }

      __builtin_amdgcn_s_setprio(1);
#pragma unroll
      for (int ks = 0; ks < 4; ++ks)
#pragma unroll
        for (int dh = 0; dh < 2; ++dh) {
          union { short8_t v; uint4 u; } vu;
          vu.u = vq[ks * 2 + dh];
          oacc[dh] = __builtin_amdgcn_mfma_f32_32x32x16_bf16(vu.v, pa[ks], oacc[dh], 0, 0, 0);
        }
      __builtin_amdgcn_s_setprio(0);
    }
  }

#pragma unroll
  for (int dh = 0; dh < 2; ++dh)
#pragma unroll
    for (int rq = 0; rq < 4; ++rq) {
      uint a0, a1;
      asm("v_cvt_pk_bf16_f32 %0, %1, %2" : "=v"(a0) : "v"(oacc[dh][4 * rq + 0]), "v"(oacc[dh][4 * rq + 1]));
      asm("v_cvt_pk_bf16_f32 %0, %1, %2" : "=v"(a1) : "v"(oacc[dh][4 * rq + 2]), "v"(oacc[dh][4 * rq + 3]));
      uint2 dd; dd.x = a0; dd.y = a1;
      *(uint2*)&obf[w][q][32 * dh + 8 * rq + 4 * hi] = dd;
    }
  if (hi == 0) mdl[w][q] = make_float2(m_run, den);
  __syncthreads();

  {
    const int qq = tid >> 3, d8 = tid & 7;
    float2 md0 = mdl[0][qq], md1 = mdl[1][qq], md2 = mdl[2][qq], md3 = mdl[3][qq];
    float mt = fmaxf(fmaxf(md0.x, md1.x), fmaxf(md2.x, md3.x));
    float w0 = exp2f((md0.x - mt) * C2);
    float w1 = exp2f((md1.x - mt) * C2);
    float w2 = exp2f((md2.x - mt) * C2);
    float w3 = exp2f((md3.x - mt) * C2);
    float inv = 1.f / (md0.y * w0 + md1.y * w1 + md2.y * w2 + md3.y * w3);

    uint4 a = *(const uint4*)&obf[0][qq][d8 * 8];
    uint4 b = *(const uint4*)&obf[1][qq][d8 * 8];
    uint4 c = *(const uint4*)&obf[2][qq][d8 * 8];
    uint4 d = *(const uint4*)&obf[3][qq][d8 * 8];
    const ushort* ap = (const ushort*)&a;
    const ushort* bp = (const ushort*)&b;
    const ushort* cp = (const ushort*)&c;
    const ushort* dp = (const ushort*)&d;
    ushort out8[8];
#pragma unroll
    for (int e = 0; e < 8; ++e) {
      float acc = bf2f(ap[e]) * w0 + bf2f(bp[e]) * w1 + bf2f(cp[e]) * w2 + bf2f(dp[e]) * w3;
      out8[e] = f2bf(acc * inv);
    }
    *(uint4*)(O + (size_t)(q0 + qq) * DMODEL + h * HDIM + d8 * 8) = *(const uint4*)out8;
  }
}

// ---------------- launch ----------------
extern "C" void kernel_launch(void* const* d_in, const int* in_sizes, int n_in,
                              void* d_out, int out_size, void* d_ws, size_t ws_size,
                              hipStream_t stream) {
  const float* x     = (const float*)d_in[0];
  const float* w_in  = (const float*)d_in[1];
  const float* w_out = (const float*)d_in[2];
  const int* icausal = (const int*)d_in[3];

  char* ws = (char*)d_ws;
  ushort* xbf    = (ushort*)(ws);                  // 4MB   (gemm1 A)
  ushort* winbf  = (ushort*)(ws + 4194304);        // 6MB   (gemm1 B)
  ushort* woutbf = (ushort*)(ws + 10485760);       // 2MB   (gemm2 B)
  ushort* qbuf   = (ushort*)(ws + 12582912);       // 4MB   (Q, stride 1024; roped in attn)
  ushort* kfrag  = (ushort*)(ws + 16777216);       // 4MB
  ushort* vfrag  = (ushort*)(ws + 20971520);       // 4MB
  ushort* obuf   = (ushort*)(ws + 25165824);       // 4MB

  cvt_all<<<6144, 256, 0, stream>>>(x, w_in, w_out, xbf, winbf, woutbf);

  gemm_abt<128, 64, 2><<<16 * 48, 256, 0, stream>>>(xbf, winbf, (void*)qbuf, kfrag, vfrag, 2048, 3072, 1024);
  attn_mfma<<<1024, 256, 0, stream>>>(qbuf, kfrag, vfrag, obuf, icausal);
  gemm_abt<64, 64, 0><<<32 * 16, 256, 0, stream>>>(obuf, woutbf, d_out, nullptr, nullptr, 2048, 1024, 1024);
}